// Round 13
// baseline (422.378 us; speedup 1.0000x reference)
//
#include <hip/hip_runtime.h>

#define NWAVE 12
#define NL 13
#define NBW (NL*NWAVE)   // 156
#define D0 36
#define D1 256
#define D2 128
#define D3 64
#define D4 32
#define AT 16            // atoms per MLP block
#define NMAX 8192
#define NBSC 128         // scatter privatization blocks
#define PI6 0.52359877559829887307f

#define F4(p) (*(const float4*)(p))
#define F2(p) (*(const float2*)(p))

__device__ __forceinline__ float wave_reduce(float v){
  #pragma unroll
  for(int o=32;o>0;o>>=1) v += __shfl_down(v,o);
  return v;
}

// ---------------- perm: stable partition of atoms by species (deterministic) ----
__global__ void perm_kernel(const int* __restrict__ species, int* __restrict__ perm,
                            int* __restrict__ counts, int N){
  __shared__ int sc[256];
  int t = threadIdx.x;
  int per = N/256;
  int c0 = 0;
  for(int k=0;k<per;k++) c0 += (species[t*per+k]==0) ? 1 : 0;
  sc[t]=c0; __syncthreads();
  for(int off=1; off<256; off<<=1){
    int add = (t>=off)? sc[t-off] : 0;
    __syncthreads();
    sc[t] += add;
    __syncthreads();
  }
  int incl = sc[t];
  int excl = incl - c0;
  int total0 = sc[255];
  if(t==0){ counts[0]=total0; counts[1]=N-total0; }
  int base0 = excl;
  int base1 = N + (t*per - excl);
  for(int k=0;k<per;k++){
    int a = t*per+k;
    if(species[a]==0) perm[base0++]=a; else perm[base1++]=a;
  }
}

// ---------------- fused weight transpose (one launch for all 4 layers) ----------
__global__ void transpose_all_kernel(const float* __restrict__ w1, const float* __restrict__ w2,
                                     const float* __restrict__ w3, const float* __restrict__ w4,
                                     float* __restrict__ t1, float* __restrict__ t2,
                                     float* __restrict__ t3, float* __restrict__ t4){
  const int E1 = 6*D0*D1, E2 = 6*D1*D2, E3 = 6*D2*D3, E4 = 6*D3*D4;
  int idx = blockIdx.x*256 + threadIdx.x;
  if(idx < E1){
    int slab = idx/(D0*D1), r = idx%(D0*D1);
    int f = r/D1, o = r%D1;
    t1[slab*D0*D1 + o*D0 + f] = w1[idx];
  } else if(idx < E1+E2){
    int k = idx-E1; int slab = k/(D1*D2), r = k%(D1*D2);
    int f = r/D2, o = r%D2;
    t2[slab*D1*D2 + o*D1 + f] = w2[k];
  } else if(idx < E1+E2+E3){
    int k = idx-E1-E2; int slab = k/(D2*D3), r = k%(D2*D3);
    int f = r/D3, o = r%D3;
    t3[slab*D2*D3 + o*D2 + f] = w3[k];
  } else if(idx < E1+E2+E3+E4){
    int k = idx-E1-E2-E3; int slab = k/(D3*D4), r = k%(D3*D4);
    int f = r/D4, o = r%D4;
    t4[slab*D3*D4 + o*D3 + f] = w4[k];
  }
}

// ---------------- K0: per-pair geometry via LDS-resident cart -------------------
__global__ void pairs_kernel(const float* __restrict__ cart, const float* __restrict__ shifts,
                             const int* __restrict__ species, const int* __restrict__ neighJ,
                             float4* __restrict__ pairbuf, int M, int N, int K){
  extern __shared__ float4 ca[];
  int t = threadIdx.x;
  for(int a=t; a<N; a+=blockDim.x)
    ca[a] = make_float4(cart[a*3+0], cart[a*3+1], cart[a*3+2], (float)species[a]);
  __syncthreads();
  int stride = gridDim.x*blockDim.x;
  for(int m = blockIdx.x*blockDim.x + t; m < M; m += stride){
    int i = m / K;
    int j = neighJ[m];
    float4 cj = ca[j];
    float4 ci = ca[i];
    float dx = ci.x - cj.x + shifts[m*3+0];
    float dy = ci.y - cj.y + shifts[m*3+1];
    float dz = ci.z - cj.z + shifts[m*3+2];
    float dist = sqrtf(dx*dx+dy*dy+dz*dz);
    float enc = (cj.w != 0.f) ? -dist : dist;
    pairbuf[m] = make_float4(dx, dy, dz, enc);
  }
}

// ---------------- K1: B[n,13,12] from pairbuf (pure linear reads) ---------------
__launch_bounds__(64)
__global__ void density_kernel(const float4* __restrict__ pairbuf,
                               const float* __restrict__ rs, const float* __restrict__ inta,
                               const float* __restrict__ cparams,
                               float* __restrict__ B, int K){
  int i = blockIdx.x;
  int t = threadIdx.x;
  __shared__ float sang[64][NL];
  __shared__ float sg[64][NWAVE];
  if(t < K){
    float4 pb = pairbuf[(size_t)i*K + t];
    float dx = pb.x, dy = pb.y, dz = pb.z;
    int sj = (pb.w < 0.f) ? 1 : 0;
    float dist = fabsf(pb.w);
    float base = 0.5f*cosf(dist*PI6)+0.5f;
    float fc = base*base;
    #pragma unroll
    for(int w=0;w<NWAVE;w++){
      float d = dist - rs[sj*NWAVE+w];
      sg[t][w] = __expf(inta[sj*NWAVE+w]*d*d)*cparams[sj*NWAVE+w];
    }
    sang[t][0]=fc;
    sang[t][1]=fc*dx;  sang[t][2]=fc*dy;  sang[t][3]=fc*dz;
    sang[t][4]=fc*dx*dx; sang[t][5]=fc*dx*dy; sang[t][6]=fc*dx*dz;
    sang[t][7]=fc*dy*dx; sang[t][8]=fc*dy*dy; sang[t][9]=fc*dy*dz;
    sang[t][10]=fc*dz*dx; sang[t][11]=fc*dz*dy; sang[t][12]=fc*dz*dz;
  }
  __syncthreads();
  for(int idx=t; idx<NBW; idx+=64){
    int l = idx/NWAVE, w = idx%NWAVE;
    float s = 0.f;
    for(int k=0;k<K;k++) s += sang[k][l]*sg[k][w];
    B[i*NBW+idx] = s;
  }
}

// ---------------- K3: per-(net,type,atom-group) MLP fwd + bwd --------------------
// 512-thread blocks (8 waves), per-thread tiles halved in rows vs R12:
// L1/dz1 2rx4c, L2/dz2 2rx2c, L3/dz3 1rx2c, L4/dz4 1rx1c. Persistent A-regs = 15.
// launch_bounds(512,4): VGPR cap 128 (live set ~80, no spill), 2 blocks/CU =
// 16 waves/CU vs R12's ~6.
__launch_bounds__(512, 4)
__global__ void mlp_kernel(const float* __restrict__ B,
    const int* __restrict__ perm, const int* __restrict__ counts,
    const float* __restrict__ w1,const float* __restrict__ b1,const float* __restrict__ a1,const float* __restrict__ g1,
    const float* __restrict__ w2,const float* __restrict__ b2,const float* __restrict__ a2,const float* __restrict__ g2,
    const float* __restrict__ w3,const float* __restrict__ b3,const float* __restrict__ a3,const float* __restrict__ g3,
    const float* __restrict__ w4,const float* __restrict__ b4,const float* __restrict__ a4,const float* __restrict__ g4,
    const float* __restrict__ wout,const float* __restrict__ bout,
    const float* __restrict__ wt1,const float* __restrict__ wt2,const float* __restrict__ wt3,const float* __restrict__ wt4,
    float* __restrict__ G1, float* __restrict__ G2, float* __restrict__ e2acc, int N)
{
  const int bpt = N/AT;
  const int net = blockIdx.x / (2*bpt);
  const int rem = blockIdx.x % (2*bpt);
  const int typ = rem / bpt;
  const int sbase = (rem % bpt)*AT;
  const int cnt = counts[typ];
  if(sbase >= cnt) return;
  const int tid = threadIdx.x;
  const int slab = net*2 + typ;

  __shared__ __align__(16) float X[AT][D0];
  __shared__ __align__(16) float H1s[AT*D1];   // also dz3 [AT][64] then dz1 [AT][256]
  __shared__ __align__(16) float H2s[AT*D2];   // also dz2 [AT][128]
  __shared__ __align__(16) float H3s[AT*D3];   // also dz4 [AT][32]
  __shared__ __align__(16) float H4s[AT*D4];
  __shared__ int atomsS[AT];

  if(tid < AT){
    int slot = sbase + tid;
    atomsS[tid] = (slot < cnt) ? perm[typ*N + slot] : -1;
  }
  __syncthreads();

  // density features
  for(int idx=tid; idx<AT*D0; idx+=512){
    int r = idx/D0, f = idx%D0;
    int a = atomsS[r];
    float v = 0.f;
    if(a >= 0){
      int w = f%NWAVE, grp = f/NWAVE;
      const float* Br = B + a*NBW;
      if(grp==0){ float b0=Br[w]; v=b0*b0; }
      else if(grp==1){
        #pragma unroll
        for(int l=1;l<4;l++){ float b0=Br[l*NWAVE+w]; v += b0*b0; }
      } else {
        #pragma unroll
        for(int l=4;l<13;l++){ float b0=Br[l*NWAVE+w]; v += b0*b0; }
      }
    }
    X[r][f] = v;
  }
  __syncthreads();

  // thread-ownership maps (same in fwd and bwd per layer), 512 threads
  const int l1c = (tid & 63)*4,  l1r = (tid >> 6)*2;   // L1/dz1: 2r x 4c
  const int l2c = (tid & 63)*2,  l2r = (tid >> 6)*2;   // L2/dz2: 2r x 2c
  const int l3c = (tid & 31)*2,  l3r = (tid >> 5);     // L3/dz3: 1r x 2c
  const int l4c = (tid & 31),    l4r = (tid >> 5);     // L4/dz4: 1r x 1c

  // persistent activation-derivative registers (live fwd -> bwd)
  float A1r[2][4], A2r[2][2], A3r[2], A4r;

  // ---- L1: 36 -> 256, tile 2x4
  {
    const float* W = w1 + slab*D0*D1;
    float acc[2][4];
    {
      float4 bv = F4(&b1[slab*D1+l1c]);
      #pragma unroll
      for(int rr=0;rr<2;rr++){ acc[rr][0]=bv.x; acc[rr][1]=bv.y; acc[rr][2]=bv.z; acc[rr][3]=bv.w; }
    }
    #pragma unroll
    for(int kk=0; kk<D0/4; kk++){
      float4 wa = F4(&W[(kk*4+0)*D1+l1c]);
      float4 wb = F4(&W[(kk*4+1)*D1+l1c]);
      float4 wc = F4(&W[(kk*4+2)*D1+l1c]);
      float4 wd = F4(&W[(kk*4+3)*D1+l1c]);
      #pragma unroll
      for(int rr=0;rr<2;rr++){
        float4 xv = F4(&X[l1r+rr][kk*4]);
        acc[rr][0] += xv.x*wa.x + xv.y*wb.x + xv.z*wc.x + xv.w*wd.x;
        acc[rr][1] += xv.x*wa.y + xv.y*wb.y + xv.z*wc.y + xv.w*wd.y;
        acc[rr][2] += xv.x*wa.z + xv.y*wb.z + xv.z*wc.z + xv.w*wd.z;
        acc[rr][3] += xv.x*wa.w + xv.y*wb.w + xv.z*wc.w + xv.w*wd.w;
      }
    }
    float4 av4 = F4(&a1[slab*D1+l1c]);
    float4 gv4 = F4(&g1[slab*D1+l1c]);
    float avv[4] = {av4.x, av4.y, av4.z, av4.w};
    float gvv[4] = {gv4.x, gv4.y, gv4.z, gv4.w};
    #pragma unroll
    for(int rr=0;rr<2;rr++){
      float hp[4];
      #pragma unroll
      for(int cc=0;cc<4;cc++){
        float u = gvv[cc]*acc[rr][cc];
        float s = 1.f/(1.f+__expf(-u));
        hp[cc] = avv[cc]*u*s;
        A1r[rr][cc] = avv[cc]*gvv[cc]*s*(1.f + u*(1.f-s));
      }
      float4 h; h.x=hp[0]; h.y=hp[1]; h.z=hp[2]; h.w=hp[3];
      *(float4*)&H1s[(l1r+rr)*D1 + l1c] = h;
    }
  }
  __syncthreads();
  // ---- L2: 256 -> 128, tile 2x2
  {
    const float* W = w2 + slab*D1*D2;
    float acc[2][2];
    {
      float2 bv = F2(&b2[slab*D2+l2c]);
      #pragma unroll
      for(int rr=0;rr<2;rr++){ acc[rr][0]=bv.x; acc[rr][1]=bv.y; }
    }
    for(int kk=0; kk<D1/4; kk++){
      float2 wa = F2(&W[(kk*4+0)*D2+l2c]);
      float2 wb = F2(&W[(kk*4+1)*D2+l2c]);
      float2 wc = F2(&W[(kk*4+2)*D2+l2c]);
      float2 wd = F2(&W[(kk*4+3)*D2+l2c]);
      #pragma unroll
      for(int rr=0;rr<2;rr++){
        float4 hv = F4(&H1s[(l2r+rr)*D1 + kk*4]);
        acc[rr][0] += hv.x*wa.x + hv.y*wb.x + hv.z*wc.x + hv.w*wd.x;
        acc[rr][1] += hv.x*wa.y + hv.y*wb.y + hv.z*wc.y + hv.w*wd.y;
      }
    }
    float2 av2 = F2(&a2[slab*D2+l2c]);
    float2 gv2 = F2(&g2[slab*D2+l2c]);
    float avv[2] = {av2.x, av2.y};
    float gvv[2] = {gv2.x, gv2.y};
    #pragma unroll
    for(int rr=0;rr<2;rr++){
      float hp[2];
      #pragma unroll
      for(int cc=0;cc<2;cc++){
        float u = gvv[cc]*acc[rr][cc];
        float s = 1.f/(1.f+__expf(-u));
        hp[cc] = avv[cc]*u*s;
        A2r[rr][cc] = avv[cc]*gvv[cc]*s*(1.f + u*(1.f-s));
      }
      float2 h; h.x=hp[0]; h.y=hp[1];
      *(float2*)&H2s[(l2r+rr)*D2 + l2c] = h;
    }
  }
  __syncthreads();
  // ---- L3: 128 -> 64, tile 1x2
  {
    const float* W = w3 + slab*D2*D3;
    float acc[2];
    {
      float2 bv = F2(&b3[slab*D3+l3c]);
      acc[0]=bv.x; acc[1]=bv.y;
    }
    for(int kk=0; kk<D2/4; kk++){
      float2 wa = F2(&W[(kk*4+0)*D3+l3c]);
      float2 wb = F2(&W[(kk*4+1)*D3+l3c]);
      float2 wc = F2(&W[(kk*4+2)*D3+l3c]);
      float2 wd = F2(&W[(kk*4+3)*D3+l3c]);
      float4 hv = F4(&H2s[l3r*D2 + kk*4]);
      acc[0] += hv.x*wa.x + hv.y*wb.x + hv.z*wc.x + hv.w*wd.x;
      acc[1] += hv.x*wa.y + hv.y*wb.y + hv.z*wc.y + hv.w*wd.y;
    }
    float2 av2 = F2(&a3[slab*D3+l3c]);
    float2 gv2 = F2(&g3[slab*D3+l3c]);
    float avv[2] = {av2.x, av2.y};
    float gvv[2] = {gv2.x, gv2.y};
    float hp[2];
    #pragma unroll
    for(int cc=0;cc<2;cc++){
      float u = gvv[cc]*acc[cc];
      float s = 1.f/(1.f+__expf(-u));
      hp[cc] = avv[cc]*u*s;
      A3r[cc] = avv[cc]*gvv[cc]*s*(1.f + u*(1.f-s));
    }
    float2 h; h.x=hp[0]; h.y=hp[1];
    *(float2*)&H3s[l3r*D3 + l3c] = h;
  }
  __syncthreads();
  // ---- L4: 64 -> 32, tile 1x1
  {
    const float* W = w4 + slab*D3*D4;
    float acc = b4[slab*D4+l4c];
    for(int kk=0; kk<D3/4; kk++){
      float wa = W[(kk*4+0)*D4+l4c];
      float wb = W[(kk*4+1)*D4+l4c];
      float wc = W[(kk*4+2)*D4+l4c];
      float wd = W[(kk*4+3)*D4+l4c];
      float4 hv = F4(&H3s[l4r*D3 + kk*4]);
      acc += hv.x*wa + hv.y*wb + hv.z*wc + hv.w*wd;
    }
    float av = a4[slab*D4+l4c], gv = g4[slab*D4+l4c];
    float u = gv*acc;
    float s = 1.f/(1.f+__expf(-u));
    H4s[l4r*D4+l4c] = av*u*s;
    A4r = av*gv*s*(1.f + u*(1.f-s));
  }
  __syncthreads();
  // ---- output layer (+ e2 for net 2)
  {
    const float* wo = wout + slab*D4;
    float val = 0.f;
    if(tid < AT){
      float s = bout[slab];
      const float* hr = &H4s[tid*D4];
      #pragma unroll
      for(int f=0;f<D4;f++) s += hr[f]*wo[f];
      if(net==2 && atomsS[tid]>=0) val = s;
    }
    if(net==2 && tid < 64){
      float v = wave_reduce(val);
      if(tid==0) atomicAdd(e2acc, v);
    }
  }
  // ---- backward for nets 0,1: G = dE/ddensity
  if(net < 2){
    float* __restrict__ Gout = (net==0)? G1 : G2;
    const float* wo = wout + slab*D4;
    __syncthreads();
    // dz4 -> H3s as [AT][32]   (ownership = L4 map, 1 elem/thread)
    H3s[l4r*D4+l4c] = wo[l4c] * A4r;
    __syncthreads();
    // dz3 = (dz4 @ W4^T)*A3 -> H1s as [AT][64]  (ownership = L3 map)
    {
      const float* WT = wt4 + slab*D4*D3;   // [32][64]
      float acc[2] = {0.f,0.f};
      #pragma unroll
      for(int kk=0; kk<D4/4; kk++){
        float2 wa = F2(&WT[(kk*4+0)*D3+l3c]);
        float2 wb = F2(&WT[(kk*4+1)*D3+l3c]);
        float2 wc = F2(&WT[(kk*4+2)*D3+l3c]);
        float2 wd = F2(&WT[(kk*4+3)*D3+l3c]);
        float4 dv = F4(&H3s[l3r*D4 + kk*4]);
        acc[0] += dv.x*wa.x + dv.y*wb.x + dv.z*wc.x + dv.w*wd.x;
        acc[1] += dv.x*wa.y + dv.y*wb.y + dv.z*wc.y + dv.w*wd.y;
      }
      float2 h;
      h.x = acc[0]*A3r[0];
      h.y = acc[1]*A3r[1];
      *(float2*)&H1s[l3r*D3 + l3c] = h;
    }
    __syncthreads();
    // dz2 = (dz3 @ W3^T)*A2 -> H2s as [AT][128]  (ownership = L2 map)
    {
      const float* WT = wt3 + slab*D3*D2;   // [64][128]
      float acc[2][2] = {{0.f,0.f},{0.f,0.f}};
      for(int kk=0; kk<D3/4; kk++){
        float2 wa = F2(&WT[(kk*4+0)*D2+l2c]);
        float2 wb = F2(&WT[(kk*4+1)*D2+l2c]);
        float2 wc = F2(&WT[(kk*4+2)*D2+l2c]);
        float2 wd = F2(&WT[(kk*4+3)*D2+l2c]);
        #pragma unroll
        for(int rr=0;rr<2;rr++){
          float4 dv = F4(&H1s[(l2r+rr)*D3 + kk*4]);
          acc[rr][0] += dv.x*wa.x + dv.y*wb.x + dv.z*wc.x + dv.w*wd.x;
          acc[rr][1] += dv.x*wa.y + dv.y*wb.y + dv.z*wc.y + dv.w*wd.y;
        }
      }
      #pragma unroll
      for(int rr=0;rr<2;rr++){
        float2 h;
        h.x = acc[rr][0]*A2r[rr][0];
        h.y = acc[rr][1]*A2r[rr][1];
        *(float2*)&H2s[(l2r+rr)*D2 + l2c] = h;
      }
    }
    __syncthreads();
    // dz1 = (dz2 @ W2^T)*A1 -> H1s as [AT][256]  (ownership = L1 map)
    {
      const float* WT = wt2 + slab*D2*D1;   // [128][256]
      float acc[2][4];
      #pragma unroll
      for(int rr=0;rr<2;rr++){ acc[rr][0]=0.f; acc[rr][1]=0.f; acc[rr][2]=0.f; acc[rr][3]=0.f; }
      for(int kk=0; kk<D2/4; kk++){
        float4 wa = F4(&WT[(kk*4+0)*D1+l1c]);
        float4 wb = F4(&WT[(kk*4+1)*D1+l1c]);
        float4 wc = F4(&WT[(kk*4+2)*D1+l1c]);
        float4 wd = F4(&WT[(kk*4+3)*D1+l1c]);
        #pragma unroll
        for(int rr=0;rr<2;rr++){
          float4 dv = F4(&H2s[(l1r+rr)*D2 + kk*4]);
          acc[rr][0] += dv.x*wa.x + dv.y*wb.x + dv.z*wc.x + dv.w*wd.x;
          acc[rr][1] += dv.x*wa.y + dv.y*wb.y + dv.z*wc.y + dv.w*wd.y;
          acc[rr][2] += dv.x*wa.z + dv.y*wb.z + dv.z*wc.z + dv.w*wd.z;
          acc[rr][3] += dv.x*wa.w + dv.y*wb.w + dv.z*wc.w + dv.w*wd.w;
        }
      }
      #pragma unroll
      for(int rr=0;rr<2;rr++){
        float4 h;
        h.x = acc[rr][0]*A1r[rr][0];
        h.y = acc[rr][1]*A1r[rr][1];
        h.z = acc[rr][2]*A1r[rr][2];
        h.w = acc[rr][3]*A1r[rr][3];
        *(float4*)&H1s[(l1r+rr)*D1 + l1c] = h;
      }
    }
    __syncthreads();
    // G = dz1 @ W1^T  (36 outputs per row)
    {
      const float* WT = wt1 + slab*D1*D0;
      for(int idx=tid; idx<AT*D0; idx+=512){
        int r = idx/D0, f = idx%D0;
        const float* dr = &H1s[r*D1];
        float acc = 0.f;
        for(int oo=0; oo<D1; oo+=4){
          const float4 dv = F4(&dr[oo]);
          acc += dv.x*WT[(oo+0)*D0+f] + dv.y*WT[(oo+1)*D0+f]
               + dv.z*WT[(oo+2)*D0+f] + dv.w*WT[(oo+3)*D0+f];
        }
        int a = atomsS[r];
        if(a >= 0) Gout[a*D0+f] = acc;
      }
    }
  }
}

// ---------------- K4: per-pair backward from pairbuf (pure linear reads) --------
__launch_bounds__(64)
__global__ void pair_back_kernel(const float4* __restrict__ pairbuf,
                                 const float* __restrict__ shifts,
                                 const float* __restrict__ rs, const float* __restrict__ inta,
                                 const float* __restrict__ cparams,
                                 const float* __restrict__ B,
                                 const float* __restrict__ G1, const float* __restrict__ G2,
                                 float* __restrict__ Ppart, float* __restrict__ jab2c,
                                 float* __restrict__ f2buf, int K){
  int i = blockIdx.x;
  int t = threadIdx.x;
  __shared__ float E1[NBW], E2[NBW];
  for(int idx=t; idx<NBW; idx+=64){
    int l = idx/NWAVE, w = idx%NWAVE;
    int grp = (l==0) ? 0 : ((l<4) ? 1 : 2);
    float b = B[i*NBW+idx];
    E1[idx] = 2.f*b*G1[i*D0 + grp*NWAVE + w];
    E2[idx] = 2.f*b*G2[i*D0 + grp*NWAVE + w];
  }
  __syncthreads();
  float p[9] = {0.f,0.f,0.f,0.f,0.f,0.f,0.f,0.f,0.f};
  float fi2[3] = {0.f,0.f,0.f};
  if(t < K){
    int m = i*K + t;
    float4 pb = pairbuf[(size_t)m];
    float dx = pb.x, dy = pb.y, dz = pb.z;
    int sj = (pb.w < 0.f) ? 1 : 0;
    float dist = fabsf(pb.w);
    float shx = shifts[m*3+0], shy = shifts[m*3+1], shz = shifts[m*3+2];
    float invd = 1.f/dist;
    float u = dist*PI6;
    float base = 0.5f*cosf(u)+0.5f;
    float fc = base*base;
    float fcp = -PI6*sinf(u)*base;      // d fc / d dist
    float gs[NWAVE], tw[NWAVE];
    #pragma unroll
    for(int w=0;w<NWAVE;w++){
      float d = dist - rs[sj*NWAVE+w];
      float ia = inta[sj*NWAVE+w];
      float g = __expf(ia*d*d)*cparams[sj*NWAVE+w];
      gs[w] = g;
      tw[w] = fcp*g + fc*(2.f*ia*d*g);  // d(fc*gauss)/d dist factor
    }
    float mono[NL] = {1.f, dx,dy,dz, dx*dx,dx*dy,dx*dz, dy*dx,dy*dy,dy*dz, dz*dx,dz*dy,dz*dz};
    float f1[3], f2[3];
    for(int net=0; net<2; net++){
      const float* E = net ? E2 : E1;
      float sl[NL];
      float radial = 0.f;
      #pragma unroll
      for(int l=0;l<NL;l++){
        float s = 0.f, q = 0.f;
        #pragma unroll
        for(int w=0;w<NWAVE;w++){
          float e = E[l*NWAVE+w];
          s += e*gs[w];
          q += e*tw[w];
        }
        sl[l] = s;
        radial += mono[l]*q;
      }
      float Ax = sl[1] + 2.f*sl[4]*dx + (sl[5]+sl[7])*dy + (sl[6]+sl[10])*dz;
      float Ay = sl[2] + (sl[5]+sl[7])*dx + 2.f*sl[8]*dy + (sl[9]+sl[11])*dz;
      float Az = sl[3] + (sl[6]+sl[10])*dx + (sl[9]+sl[11])*dy + 2.f*sl[12]*dz;
      float rr = radial*invd;
      float fx = dx*rr + fc*Ax;
      float fy = dy*rr + fc*Ay;
      float fz = dz*rr + fc*Az;
      if(net==0){ f1[0]=fx; f1[1]=fy; f1[2]=fz; }
      else      { f2[0]=fx; f2[1]=fy; f2[2]=fz; }
    }
    // cart[i]-cart[j] = dvec - shift ;  P += (cart_i - cart_j) (x) f1
    float cx = dx-shx, cy = dy-shy, cz = dz-shz;
    p[0]=cx*f1[0]; p[1]=cx*f1[1]; p[2]=cx*f1[2];
    p[3]=cy*f1[0]; p[4]=cy*f1[1]; p[5]=cy*f1[2];
    p[6]=cz*f1[0]; p[7]=cz*f1[1]; p[8]=cz*f1[2];
    // per-pair neighbor force (gathered by scatter_kernel in LDS)
    float* fb = f2buf + (size_t)m*3;
    fb[0]=f2[0]; fb[1]=f2[1]; fb[2]=f2[2];
    fi2[0]=f2[0]; fi2[1]=f2[1]; fi2[2]=f2[2];
  }
  #pragma unroll
  for(int k=0;k<9;k++){
    float v = wave_reduce(p[k]);
    if(t==0) Ppart[(size_t)i*9+k] = v;
  }
  #pragma unroll
  for(int c=0;c<3;c++){
    float v = wave_reduce(fi2[c]);
    if(t==0) jab2c[(size_t)i*3+c] = v;
  }
}

// ---------------- K5: LDS-privatized scatter of -f2 onto neighbor atoms ---------
__global__ void scatter_kernel(const int* __restrict__ neighJ, const float* __restrict__ f2buf,
                               float* __restrict__ jpart, int M, int N){
  __shared__ float lds[NMAX];
  int b = blockIdx.x, t = threadIdx.x;
  int chunk = (M + gridDim.x - 1) / gridDim.x;
  int m0 = b*chunk;
  int m1 = m0 + chunk; if(m1 > M) m1 = M;
  for(int c=0;c<3;c++){
    for(int n=t; n<N; n+=256) lds[n] = 0.f;
    __syncthreads();
    for(int m=m0+t; m<m1; m+=256)
      atomicAdd(&lds[neighJ[m]], -f2buf[(size_t)m*3+c]);
    __syncthreads();
    float* dst = jpart + ((size_t)b*3 + c)*N;
    for(int n=t; n<N; n+=256) dst[n] = lds[n];
    __syncthreads();
  }
}

// ---------------- K6: jab2 total -> S2 partials; Ppart -> P sum ------------------
__global__ void reduce_kernel(const float* __restrict__ Ppart, const float* __restrict__ jab2c,
                              const float* __restrict__ jpart,
                              float* __restrict__ Pacc, float* __restrict__ S2, int N){
  __shared__ float red[256];
  int tid = threadIdx.x;
  float s2[9] = {0.f,0.f,0.f,0.f,0.f,0.f,0.f,0.f,0.f};
  float pp[9] = {0.f,0.f,0.f,0.f,0.f,0.f,0.f,0.f,0.f};
  for(int n = blockIdx.x*256 + tid; n < N; n += gridDim.x*256){
    float x = jab2c[n*3+0], y = jab2c[n*3+1], z = jab2c[n*3+2];
    for(int b=0;b<NBSC;b++){
      const float* jp = jpart + (size_t)b*3*N;
      x += jp[0*(size_t)N + n];
      y += jp[1*(size_t)N + n];
      z += jp[2*(size_t)N + n];
    }
    s2[0]+=x*x; s2[1]+=x*y; s2[2]+=x*z;
    s2[3]+=y*x; s2[4]+=y*y; s2[5]+=y*z;
    s2[6]+=z*x; s2[7]+=z*y; s2[8]+=z*z;
    const float* pr = Ppart + (size_t)n*9;
    #pragma unroll
    for(int k=0;k<9;k++) pp[k] += pr[k];
  }
  #pragma unroll
  for(int k=0;k<9;k++){
    red[tid]=s2[k]; __syncthreads();
    for(int off=128; off>0; off>>=1){
      if(tid<off) red[tid]+=red[tid+off];
      __syncthreads();
    }
    if(tid==0) atomicAdd(&S2[k], red[0]);
    __syncthreads();
    red[tid]=pp[k]; __syncthreads();
    for(int off=128; off>0; off>>=1){
      if(tid<off) red[tid]+=red[tid+off];
      __syncthreads();
    }
    if(tid==0) atomicAdd(&Pacc[k], red[0]);
    __syncthreads();
  }
}

// ---------------- K7: assemble --------------------------------------------------
__global__ void final_kernel(const float* __restrict__ Pacc, const float* __restrict__ S2,
                             const float* __restrict__ e2acc, float* __restrict__ out){
  int tid = threadIdx.x;
  if(tid < 9){
    int a = tid/3, b = tid%3;
    float v = Pacc[a*3+b] + Pacc[b*3+a] + S2[tid];
    if(a==b) v += e2acc[0];
    out[tid] = v;
  }
}

extern "C" void kernel_launch(void* const* d_in, const int* in_sizes, int n_in,
                              void* d_out, int out_size, void* d_ws, size_t ws_size,
                              hipStream_t stream){
  const float* cart    = (const float*)d_in[0];
  const float* shifts  = (const float*)d_in[1];
  const float* rs      = (const float*)d_in[2];
  const float* inta    = (const float*)d_in[3];
  const float* cparams = (const float*)d_in[4];
  const float* w1 = (const float*)d_in[5];
  const float* b1 = (const float*)d_in[6];
  const float* a1 = (const float*)d_in[7];
  const float* g1 = (const float*)d_in[8];
  const float* w2 = (const float*)d_in[9];
  const float* b2 = (const float*)d_in[10];
  const float* a2 = (const float*)d_in[11];
  const float* g2 = (const float*)d_in[12];
  const float* w3 = (const float*)d_in[13];
  const float* b3 = (const float*)d_in[14];
  const float* a3 = (const float*)d_in[15];
  const float* g3 = (const float*)d_in[16];
  const float* w4 = (const float*)d_in[17];
  const float* b4 = (const float*)d_in[18];
  const float* a4 = (const float*)d_in[19];
  const float* g4 = (const float*)d_in[20];
  const float* wout = (const float*)d_in[21];
  const float* bout = (const float*)d_in[22];
  const int* species = (const int*)d_in[23];
  const int* neigh   = (const int*)d_in[24];
  float* out = (float*)d_out;

  const int N = in_sizes[0]/3;
  const int M = in_sizes[24]/2;
  const int K = M/N;
  const int* neighJ = neigh + M;

  char* base = (char*)d_ws;
  size_t off = 0;
  auto alloc = [&](size_t bytes)->void*{
    void* p = base + off;
    off = (off + bytes + 255) & ~(size_t)255;
    return p;
  };
  float*  Bws    = (float*)alloc((size_t)N*NBW*4);
  float*  G1ws   = (float*)alloc((size_t)N*D0*4);
  float*  G2ws   = (float*)alloc((size_t)N*D0*4);
  float*  Ppart  = (float*)alloc((size_t)N*9*4);
  float*  jab2c  = (float*)alloc((size_t)N*3*4);
  float*  f2buf  = (float*)alloc((size_t)M*3*4);
  float4* pairbuf= (float4*)alloc((size_t)M*16);
  float*  jpart  = (float*)alloc((size_t)NBSC*3*N*4);
  float*  acc    = (float*)alloc(32*4);          // P[0..8], S2[9..17], e2[18]
  int*    counts = (int*)alloc(2*4);
  int*    perm   = (int*)alloc((size_t)2*N*4);
  float*  WT1    = (float*)alloc((size_t)6*D0*D1*4);
  float*  WT2    = (float*)alloc((size_t)6*D1*D2*4);
  float*  WT3    = (float*)alloc((size_t)6*D2*D3*4);
  float*  WT4    = (float*)alloc((size_t)6*D3*D4*4);

  hipMemsetAsync(acc, 0, 32*4, stream);

  // allow >64KB dynamic LDS for pairs_kernel (160KB/CU on gfx950)
  size_t ldsBytes = (size_t)N*16;
  hipFuncSetAttribute((const void*)pairs_kernel,
                      hipFuncAttributeMaxDynamicSharedMemorySize, (int)ldsBytes);

  const int ETOT = 6*(D0*D1 + D1*D2 + D2*D3 + D3*D4);
  perm_kernel<<<1,256,0,stream>>>(species, perm, counts, N);
  transpose_all_kernel<<<(ETOT+255)/256,256,0,stream>>>(w1,w2,w3,w4, WT1,WT2,WT3,WT4);
  pairs_kernel<<<256,1024,ldsBytes,stream>>>(cart, shifts, species, neighJ, pairbuf, M, N, K);
  density_kernel<<<N,64,0,stream>>>(pairbuf, rs, inta, cparams, Bws, K);
  mlp_kernel<<<3*2*(N/AT),512,0,stream>>>(Bws, perm, counts,
      w1,b1,a1,g1, w2,b2,a2,g2, w3,b3,a3,g3, w4,b4,a4,g4, wout,bout,
      WT1,WT2,WT3,WT4, G1ws,G2ws, acc+18, N);
  pair_back_kernel<<<N,64,0,stream>>>(pairbuf, shifts, rs, inta, cparams,
                                      Bws, G1ws, G2ws, Ppart, jab2c, f2buf, K);
  scatter_kernel<<<NBSC,256,0,stream>>>(neighJ, f2buf, jpart, M, N);
  reduce_kernel<<<64,256,0,stream>>>(Ppart, jab2c, jpart, acc, acc+9, N);
  final_kernel<<<1,64,0,stream>>>(acc, acc+9, acc+18, out);
}

// Round 14
// 400.656 us; speedup vs baseline: 1.0542x; 1.0542x over previous
//
#include <hip/hip_runtime.h>

#define NWAVE 12
#define NL 13
#define NBW (NL*NWAVE)   // 156
#define D0 36
#define D1 256
#define D2 128
#define D3 64
#define D4 32
#define AT 8             // atoms per MLP block (LDS 16.5KB; halved tiles, VGPR ~100)
#define NMAX 8192
#define NBSC 128         // scatter privatization blocks
#define PI6 0.52359877559829887307f

#define F4(p) (*(const float4*)(p))
#define F2(p) (*(const float2*)(p))

__device__ __forceinline__ float wave_reduce(float v){
  #pragma unroll
  for(int o=32;o>0;o>>=1) v += __shfl_down(v,o);
  return v;
}

// ---------------- perm: stable partition of atoms by species (deterministic) ----
__global__ void perm_kernel(const int* __restrict__ species, int* __restrict__ perm,
                            int* __restrict__ counts, int N){
  __shared__ int sc[256];
  int t = threadIdx.x;
  int per = N/256;
  int c0 = 0;
  for(int k=0;k<per;k++) c0 += (species[t*per+k]==0) ? 1 : 0;
  sc[t]=c0; __syncthreads();
  for(int off=1; off<256; off<<=1){
    int add = (t>=off)? sc[t-off] : 0;
    __syncthreads();
    sc[t] += add;
    __syncthreads();
  }
  int incl = sc[t];
  int excl = incl - c0;
  int total0 = sc[255];
  if(t==0){ counts[0]=total0; counts[1]=N-total0; }
  int base0 = excl;
  int base1 = N + (t*per - excl);
  for(int k=0;k<per;k++){
    int a = t*per+k;
    if(species[a]==0) perm[base0++]=a; else perm[base1++]=a;
  }
}

// ---------------- fused weight transpose (one launch for all 4 layers) ----------
__global__ void transpose_all_kernel(const float* __restrict__ w1, const float* __restrict__ w2,
                                     const float* __restrict__ w3, const float* __restrict__ w4,
                                     float* __restrict__ t1, float* __restrict__ t2,
                                     float* __restrict__ t3, float* __restrict__ t4){
  const int E1 = 6*D0*D1, E2 = 6*D1*D2, E3 = 6*D2*D3, E4 = 6*D3*D4;
  int idx = blockIdx.x*256 + threadIdx.x;
  if(idx < E1){
    int slab = idx/(D0*D1), r = idx%(D0*D1);
    int f = r/D1, o = r%D1;
    t1[slab*D0*D1 + o*D0 + f] = w1[idx];
  } else if(idx < E1+E2){
    int k = idx-E1; int slab = k/(D1*D2), r = k%(D1*D2);
    int f = r/D2, o = r%D2;
    t2[slab*D1*D2 + o*D1 + f] = w2[k];
  } else if(idx < E1+E2+E3){
    int k = idx-E1-E2; int slab = k/(D2*D3), r = k%(D2*D3);
    int f = r/D3, o = r%D3;
    t3[slab*D2*D3 + o*D2 + f] = w3[k];
  } else if(idx < E1+E2+E3+E4){
    int k = idx-E1-E2-E3; int slab = k/(D3*D4), r = k%(D3*D4);
    int f = r/D4, o = r%D4;
    t4[slab*D3*D4 + o*D3 + f] = w4[k];
  }
}

// ---------------- K0: per-pair geometry via LDS-resident cart -------------------
__global__ void pairs_kernel(const float* __restrict__ cart, const float* __restrict__ shifts,
                             const int* __restrict__ species, const int* __restrict__ neighJ,
                             float4* __restrict__ pairbuf, int M, int N, int K){
  extern __shared__ float4 ca[];
  int t = threadIdx.x;
  for(int a=t; a<N; a+=blockDim.x)
    ca[a] = make_float4(cart[a*3+0], cart[a*3+1], cart[a*3+2], (float)species[a]);
  __syncthreads();
  int stride = gridDim.x*blockDim.x;
  for(int m = blockIdx.x*blockDim.x + t; m < M; m += stride){
    int i = m / K;
    int j = neighJ[m];
    float4 cj = ca[j];
    float4 ci = ca[i];
    float dx = ci.x - cj.x + shifts[m*3+0];
    float dy = ci.y - cj.y + shifts[m*3+1];
    float dz = ci.z - cj.z + shifts[m*3+2];
    float dist = sqrtf(dx*dx+dy*dy+dz*dz);
    float enc = (cj.w != 0.f) ? -dist : dist;
    pairbuf[m] = make_float4(dx, dy, dz, enc);
  }
}

// ---------------- K1: B[n,13,12] from pairbuf (pure linear reads) ---------------
__launch_bounds__(64)
__global__ void density_kernel(const float4* __restrict__ pairbuf,
                               const float* __restrict__ rs, const float* __restrict__ inta,
                               const float* __restrict__ cparams,
                               float* __restrict__ B, int K){
  int i = blockIdx.x;
  int t = threadIdx.x;
  __shared__ float sang[64][NL];
  __shared__ float sg[64][NWAVE];
  if(t < K){
    float4 pb = pairbuf[(size_t)i*K + t];
    float dx = pb.x, dy = pb.y, dz = pb.z;
    int sj = (pb.w < 0.f) ? 1 : 0;
    float dist = fabsf(pb.w);
    float base = 0.5f*cosf(dist*PI6)+0.5f;
    float fc = base*base;
    #pragma unroll
    for(int w=0;w<NWAVE;w++){
      float d = dist - rs[sj*NWAVE+w];
      sg[t][w] = __expf(inta[sj*NWAVE+w]*d*d)*cparams[sj*NWAVE+w];
    }
    sang[t][0]=fc;
    sang[t][1]=fc*dx;  sang[t][2]=fc*dy;  sang[t][3]=fc*dz;
    sang[t][4]=fc*dx*dx; sang[t][5]=fc*dx*dy; sang[t][6]=fc*dx*dz;
    sang[t][7]=fc*dy*dx; sang[t][8]=fc*dy*dy; sang[t][9]=fc*dy*dz;
    sang[t][10]=fc*dz*dx; sang[t][11]=fc*dz*dy; sang[t][12]=fc*dz*dz;
  }
  __syncthreads();
  for(int idx=t; idx<NBW; idx+=64){
    int l = idx/NWAVE, w = idx%NWAVE;
    float s = 0.f;
    for(int k=0;k<K;k++) s += sang[k][l]*sg[k][w];
    B[i*NBW+idx] = s;
  }
}

// ---------------- K3: per-(net,type,atom-group) MLP fwd + bwd --------------------
// AT=8, 256 threads, halved tiles (L1 2rx4c, L2 2rx2c, L3 1rx2c, L4 1rx1c).
// LDS 16.5KB; launch_bounds(256,1) = NO VGPR cap (the proven no-spill setting;
// (256,2)/(512,4) caps at 128/64 and spilled in R10/R13). Natural VGPR ~100 ->
// 4-5 blocks/CU by registers, 9 by LDS; grid 3072 working blocks.
__launch_bounds__(256, 1)
__global__ void mlp_kernel(const float* __restrict__ B,
    const int* __restrict__ perm, const int* __restrict__ counts,
    const float* __restrict__ w1,const float* __restrict__ b1,const float* __restrict__ a1,const float* __restrict__ g1,
    const float* __restrict__ w2,const float* __restrict__ b2,const float* __restrict__ a2,const float* __restrict__ g2,
    const float* __restrict__ w3,const float* __restrict__ b3,const float* __restrict__ a3,const float* __restrict__ g3,
    const float* __restrict__ w4,const float* __restrict__ b4,const float* __restrict__ a4,const float* __restrict__ g4,
    const float* __restrict__ wout,const float* __restrict__ bout,
    const float* __restrict__ wt1,const float* __restrict__ wt2,const float* __restrict__ wt3,const float* __restrict__ wt4,
    float* __restrict__ G1, float* __restrict__ G2, float* __restrict__ e2acc, int N)
{
  const int bpt = N/AT;
  const int net = blockIdx.x / (2*bpt);
  const int rem = blockIdx.x % (2*bpt);
  const int typ = rem / bpt;
  const int sbase = (rem % bpt)*AT;
  const int cnt = counts[typ];
  if(sbase >= cnt) return;
  const int tid = threadIdx.x;
  const int slab = net*2 + typ;

  __shared__ __align__(16) float X[AT][D0];
  __shared__ __align__(16) float H1s[AT*D1];   // also dz3 [AT][64] then dz1 [AT][256]
  __shared__ __align__(16) float H2s[AT*D2];   // also dz2 [AT][128]
  __shared__ __align__(16) float H3s[AT*D3];   // also dz4 [AT][32]
  __shared__ __align__(16) float H4s[AT*D4];
  __shared__ int atomsS[AT];

  if(tid < AT){
    int slot = sbase + tid;
    atomsS[tid] = (slot < cnt) ? perm[typ*N + slot] : -1;
  }
  __syncthreads();

  // density features
  for(int idx=tid; idx<AT*D0; idx+=256){
    int r = idx/D0, f = idx%D0;
    int a = atomsS[r];
    float v = 0.f;
    if(a >= 0){
      int w = f%NWAVE, grp = f/NWAVE;
      const float* Br = B + a*NBW;
      if(grp==0){ float b0=Br[w]; v=b0*b0; }
      else if(grp==1){
        #pragma unroll
        for(int l=1;l<4;l++){ float b0=Br[l*NWAVE+w]; v += b0*b0; }
      } else {
        #pragma unroll
        for(int l=4;l<13;l++){ float b0=Br[l*NWAVE+w]; v += b0*b0; }
      }
    }
    X[r][f] = v;
  }
  __syncthreads();

  // thread-ownership maps (same in fwd and bwd per layer), 256 threads, AT=8
  const int l1c = (tid & 63)*4,  l1r = (tid >> 6)*2;   // L1/dz1: 2r x 4c (rows 0..7)
  const int l2c = (tid & 63)*2,  l2r = (tid >> 6)*2;   // L2/dz2: 2r x 2c
  const int l3c = (tid & 31)*2,  l3r = (tid >> 5);     // L3/dz3: 1r x 2c (rows 0..7)
  const int l4c = (tid & 31),    l4r = (tid >> 5);     // L4/dz4: 1r x 1c

  // persistent activation-derivative registers (live fwd -> bwd)
  float A1r[2][4], A2r[2][2], A3r[2], A4r;

  // ---- L1: 36 -> 256, tile 2x4
  {
    const float* W = w1 + slab*D0*D1;
    float acc[2][4];
    {
      float4 bv = F4(&b1[slab*D1+l1c]);
      #pragma unroll
      for(int rr=0;rr<2;rr++){ acc[rr][0]=bv.x; acc[rr][1]=bv.y; acc[rr][2]=bv.z; acc[rr][3]=bv.w; }
    }
    #pragma unroll
    for(int kk=0; kk<D0/4; kk++){
      float4 wa = F4(&W[(kk*4+0)*D1+l1c]);
      float4 wb = F4(&W[(kk*4+1)*D1+l1c]);
      float4 wc = F4(&W[(kk*4+2)*D1+l1c]);
      float4 wd = F4(&W[(kk*4+3)*D1+l1c]);
      #pragma unroll
      for(int rr=0;rr<2;rr++){
        float4 xv = F4(&X[l1r+rr][kk*4]);
        acc[rr][0] += xv.x*wa.x + xv.y*wb.x + xv.z*wc.x + xv.w*wd.x;
        acc[rr][1] += xv.x*wa.y + xv.y*wb.y + xv.z*wc.y + xv.w*wd.y;
        acc[rr][2] += xv.x*wa.z + xv.y*wb.z + xv.z*wc.z + xv.w*wd.z;
        acc[rr][3] += xv.x*wa.w + xv.y*wb.w + xv.z*wc.w + xv.w*wd.w;
      }
    }
    float4 av4 = F4(&a1[slab*D1+l1c]);
    float4 gv4 = F4(&g1[slab*D1+l1c]);
    float avv[4] = {av4.x, av4.y, av4.z, av4.w};
    float gvv[4] = {gv4.x, gv4.y, gv4.z, gv4.w};
    #pragma unroll
    for(int rr=0;rr<2;rr++){
      float hp[4];
      #pragma unroll
      for(int cc=0;cc<4;cc++){
        float u = gvv[cc]*acc[rr][cc];
        float s = 1.f/(1.f+__expf(-u));
        hp[cc] = avv[cc]*u*s;
        A1r[rr][cc] = avv[cc]*gvv[cc]*s*(1.f + u*(1.f-s));
      }
      float4 h; h.x=hp[0]; h.y=hp[1]; h.z=hp[2]; h.w=hp[3];
      *(float4*)&H1s[(l1r+rr)*D1 + l1c] = h;
    }
  }
  __syncthreads();
  // ---- L2: 256 -> 128, tile 2x2
  {
    const float* W = w2 + slab*D1*D2;
    float acc[2][2];
    {
      float2 bv = F2(&b2[slab*D2+l2c]);
      #pragma unroll
      for(int rr=0;rr<2;rr++){ acc[rr][0]=bv.x; acc[rr][1]=bv.y; }
    }
    for(int kk=0; kk<D1/4; kk++){
      float2 wa = F2(&W[(kk*4+0)*D2+l2c]);
      float2 wb = F2(&W[(kk*4+1)*D2+l2c]);
      float2 wc = F2(&W[(kk*4+2)*D2+l2c]);
      float2 wd = F2(&W[(kk*4+3)*D2+l2c]);
      #pragma unroll
      for(int rr=0;rr<2;rr++){
        float4 hv = F4(&H1s[(l2r+rr)*D1 + kk*4]);
        acc[rr][0] += hv.x*wa.x + hv.y*wb.x + hv.z*wc.x + hv.w*wd.x;
        acc[rr][1] += hv.x*wa.y + hv.y*wb.y + hv.z*wc.y + hv.w*wd.y;
      }
    }
    float2 av2 = F2(&a2[slab*D2+l2c]);
    float2 gv2 = F2(&g2[slab*D2+l2c]);
    float avv[2] = {av2.x, av2.y};
    float gvv[2] = {gv2.x, gv2.y};
    #pragma unroll
    for(int rr=0;rr<2;rr++){
      float hp[2];
      #pragma unroll
      for(int cc=0;cc<2;cc++){
        float u = gvv[cc]*acc[rr][cc];
        float s = 1.f/(1.f+__expf(-u));
        hp[cc] = avv[cc]*u*s;
        A2r[rr][cc] = avv[cc]*gvv[cc]*s*(1.f + u*(1.f-s));
      }
      float2 h; h.x=hp[0]; h.y=hp[1];
      *(float2*)&H2s[(l2r+rr)*D2 + l2c] = h;
    }
  }
  __syncthreads();
  // ---- L3: 128 -> 64, tile 1x2
  {
    const float* W = w3 + slab*D2*D3;
    float acc[2];
    {
      float2 bv = F2(&b3[slab*D3+l3c]);
      acc[0]=bv.x; acc[1]=bv.y;
    }
    for(int kk=0; kk<D2/4; kk++){
      float2 wa = F2(&W[(kk*4+0)*D3+l3c]);
      float2 wb = F2(&W[(kk*4+1)*D3+l3c]);
      float2 wc = F2(&W[(kk*4+2)*D3+l3c]);
      float2 wd = F2(&W[(kk*4+3)*D3+l3c]);
      float4 hv = F4(&H2s[l3r*D2 + kk*4]);
      acc[0] += hv.x*wa.x + hv.y*wb.x + hv.z*wc.x + hv.w*wd.x;
      acc[1] += hv.x*wa.y + hv.y*wb.y + hv.z*wc.y + hv.w*wd.y;
    }
    float2 av2 = F2(&a3[slab*D3+l3c]);
    float2 gv2 = F2(&g3[slab*D3+l3c]);
    float avv[2] = {av2.x, av2.y};
    float gvv[2] = {gv2.x, gv2.y};
    float hp[2];
    #pragma unroll
    for(int cc=0;cc<2;cc++){
      float u = gvv[cc]*acc[cc];
      float s = 1.f/(1.f+__expf(-u));
      hp[cc] = avv[cc]*u*s;
      A3r[cc] = avv[cc]*gvv[cc]*s*(1.f + u*(1.f-s));
    }
    float2 h; h.x=hp[0]; h.y=hp[1];
    *(float2*)&H3s[l3r*D3 + l3c] = h;
  }
  __syncthreads();
  // ---- L4: 64 -> 32, tile 1x1
  {
    const float* W = w4 + slab*D3*D4;
    float acc = b4[slab*D4+l4c];
    for(int kk=0; kk<D3/4; kk++){
      float wa = W[(kk*4+0)*D4+l4c];
      float wb = W[(kk*4+1)*D4+l4c];
      float wc = W[(kk*4+2)*D4+l4c];
      float wd = W[(kk*4+3)*D4+l4c];
      float4 hv = F4(&H3s[l4r*D3 + kk*4]);
      acc += hv.x*wa + hv.y*wb + hv.z*wc + hv.w*wd;
    }
    float av = a4[slab*D4+l4c], gv = g4[slab*D4+l4c];
    float u = gv*acc;
    float s = 1.f/(1.f+__expf(-u));
    H4s[l4r*D4+l4c] = av*u*s;
    A4r = av*gv*s*(1.f + u*(1.f-s));
  }
  __syncthreads();
  // ---- output layer (+ e2 for net 2)
  {
    const float* wo = wout + slab*D4;
    float val = 0.f;
    if(tid < AT){
      float s = bout[slab];
      const float* hr = &H4s[tid*D4];
      #pragma unroll
      for(int f=0;f<D4;f++) s += hr[f]*wo[f];
      if(net==2 && atomsS[tid]>=0) val = s;
    }
    if(net==2 && tid < 64){
      float v = wave_reduce(val);
      if(tid==0) atomicAdd(e2acc, v);
    }
  }
  // ---- backward for nets 0,1: G = dE/ddensity
  if(net < 2){
    float* __restrict__ Gout = (net==0)? G1 : G2;
    const float* wo = wout + slab*D4;
    __syncthreads();
    // dz4 -> H3s as [AT][32]   (ownership = L4 map, 1 elem/thread)
    H3s[l4r*D4+l4c] = wo[l4c] * A4r;
    __syncthreads();
    // dz3 = (dz4 @ W4^T)*A3 -> H1s as [AT][64]  (ownership = L3 map)
    {
      const float* WT = wt4 + slab*D4*D3;   // [32][64]
      float acc[2] = {0.f,0.f};
      #pragma unroll
      for(int kk=0; kk<D4/4; kk++){
        float2 wa = F2(&WT[(kk*4+0)*D3+l3c]);
        float2 wb = F2(&WT[(kk*4+1)*D3+l3c]);
        float2 wc = F2(&WT[(kk*4+2)*D3+l3c]);
        float2 wd = F2(&WT[(kk*4+3)*D3+l3c]);
        float4 dv = F4(&H3s[l3r*D4 + kk*4]);
        acc[0] += dv.x*wa.x + dv.y*wb.x + dv.z*wc.x + dv.w*wd.x;
        acc[1] += dv.x*wa.y + dv.y*wb.y + dv.z*wc.y + dv.w*wd.y;
      }
      float2 h;
      h.x = acc[0]*A3r[0];
      h.y = acc[1]*A3r[1];
      *(float2*)&H1s[l3r*D3 + l3c] = h;
    }
    __syncthreads();
    // dz2 = (dz3 @ W3^T)*A2 -> H2s as [AT][128]  (ownership = L2 map)
    {
      const float* WT = wt3 + slab*D3*D2;   // [64][128]
      float acc[2][2] = {{0.f,0.f},{0.f,0.f}};
      for(int kk=0; kk<D3/4; kk++){
        float2 wa = F2(&WT[(kk*4+0)*D2+l2c]);
        float2 wb = F2(&WT[(kk*4+1)*D2+l2c]);
        float2 wc = F2(&WT[(kk*4+2)*D2+l2c]);
        float2 wd = F2(&WT[(kk*4+3)*D2+l2c]);
        #pragma unroll
        for(int rr=0;rr<2;rr++){
          float4 dv = F4(&H1s[(l2r+rr)*D3 + kk*4]);
          acc[rr][0] += dv.x*wa.x + dv.y*wb.x + dv.z*wc.x + dv.w*wd.x;
          acc[rr][1] += dv.x*wa.y + dv.y*wb.y + dv.z*wc.y + dv.w*wd.y;
        }
      }
      #pragma unroll
      for(int rr=0;rr<2;rr++){
        float2 h;
        h.x = acc[rr][0]*A2r[rr][0];
        h.y = acc[rr][1]*A2r[rr][1];
        *(float2*)&H2s[(l2r+rr)*D2 + l2c] = h;
      }
    }
    __syncthreads();
    // dz1 = (dz2 @ W2^T)*A1 -> H1s as [AT][256]  (ownership = L1 map)
    {
      const float* WT = wt2 + slab*D2*D1;   // [128][256]
      float acc[2][4];
      #pragma unroll
      for(int rr=0;rr<2;rr++){ acc[rr][0]=0.f; acc[rr][1]=0.f; acc[rr][2]=0.f; acc[rr][3]=0.f; }
      for(int kk=0; kk<D2/4; kk++){
        float4 wa = F4(&WT[(kk*4+0)*D1+l1c]);
        float4 wb = F4(&WT[(kk*4+1)*D1+l1c]);
        float4 wc = F4(&WT[(kk*4+2)*D1+l1c]);
        float4 wd = F4(&WT[(kk*4+3)*D1+l1c]);
        #pragma unroll
        for(int rr=0;rr<2;rr++){
          float4 dv = F4(&H2s[(l1r+rr)*D2 + kk*4]);
          acc[rr][0] += dv.x*wa.x + dv.y*wb.x + dv.z*wc.x + dv.w*wd.x;
          acc[rr][1] += dv.x*wa.y + dv.y*wb.y + dv.z*wc.y + dv.w*wd.y;
          acc[rr][2] += dv.x*wa.z + dv.y*wb.z + dv.z*wc.z + dv.w*wd.z;
          acc[rr][3] += dv.x*wa.w + dv.y*wb.w + dv.z*wc.w + dv.w*wd.w;
        }
      }
      #pragma unroll
      for(int rr=0;rr<2;rr++){
        float4 h;
        h.x = acc[rr][0]*A1r[rr][0];
        h.y = acc[rr][1]*A1r[rr][1];
        h.z = acc[rr][2]*A1r[rr][2];
        h.w = acc[rr][3]*A1r[rr][3];
        *(float4*)&H1s[(l1r+rr)*D1 + l1c] = h;
      }
    }
    __syncthreads();
    // G = dz1 @ W1^T  (36 outputs per row)
    {
      const float* WT = wt1 + slab*D1*D0;
      for(int idx=tid; idx<AT*D0; idx+=256){
        int r = idx/D0, f = idx%D0;
        const float* dr = &H1s[r*D1];
        float acc = 0.f;
        for(int oo=0; oo<D1; oo+=4){
          const float4 dv = F4(&dr[oo]);
          acc += dv.x*WT[(oo+0)*D0+f] + dv.y*WT[(oo+1)*D0+f]
               + dv.z*WT[(oo+2)*D0+f] + dv.w*WT[(oo+3)*D0+f];
        }
        int a = atomsS[r];
        if(a >= 0) Gout[a*D0+f] = acc;
      }
    }
  }
}

// ---------------- K4: per-pair backward from pairbuf (pure linear reads) --------
__launch_bounds__(64)
__global__ void pair_back_kernel(const float4* __restrict__ pairbuf,
                                 const float* __restrict__ shifts,
                                 const float* __restrict__ rs, const float* __restrict__ inta,
                                 const float* __restrict__ cparams,
                                 const float* __restrict__ B,
                                 const float* __restrict__ G1, const float* __restrict__ G2,
                                 float* __restrict__ Ppart, float* __restrict__ jab2c,
                                 float* __restrict__ f2buf, int K){
  int i = blockIdx.x;
  int t = threadIdx.x;
  __shared__ float E1[NBW], E2[NBW];
  for(int idx=t; idx<NBW; idx+=64){
    int l = idx/NWAVE, w = idx%NWAVE;
    int grp = (l==0) ? 0 : ((l<4) ? 1 : 2);
    float b = B[i*NBW+idx];
    E1[idx] = 2.f*b*G1[i*D0 + grp*NWAVE + w];
    E2[idx] = 2.f*b*G2[i*D0 + grp*NWAVE + w];
  }
  __syncthreads();
  float p[9] = {0.f,0.f,0.f,0.f,0.f,0.f,0.f,0.f,0.f};
  float fi2[3] = {0.f,0.f,0.f};
  if(t < K){
    int m = i*K + t;
    float4 pb = pairbuf[(size_t)m];
    float dx = pb.x, dy = pb.y, dz = pb.z;
    int sj = (pb.w < 0.f) ? 1 : 0;
    float dist = fabsf(pb.w);
    float shx = shifts[m*3+0], shy = shifts[m*3+1], shz = shifts[m*3+2];
    float invd = 1.f/dist;
    float u = dist*PI6;
    float base = 0.5f*cosf(u)+0.5f;
    float fc = base*base;
    float fcp = -PI6*sinf(u)*base;      // d fc / d dist
    float gs[NWAVE], tw[NWAVE];
    #pragma unroll
    for(int w=0;w<NWAVE;w++){
      float d = dist - rs[sj*NWAVE+w];
      float ia = inta[sj*NWAVE+w];
      float g = __expf(ia*d*d)*cparams[sj*NWAVE+w];
      gs[w] = g;
      tw[w] = fcp*g + fc*(2.f*ia*d*g);  // d(fc*gauss)/d dist factor
    }
    float mono[NL] = {1.f, dx,dy,dz, dx*dx,dx*dy,dx*dz, dy*dx,dy*dy,dy*dz, dz*dx,dz*dy,dz*dz};
    float f1[3], f2[3];
    for(int net=0; net<2; net++){
      const float* E = net ? E2 : E1;
      float sl[NL];
      float radial = 0.f;
      #pragma unroll
      for(int l=0;l<NL;l++){
        float s = 0.f, q = 0.f;
        #pragma unroll
        for(int w=0;w<NWAVE;w++){
          float e = E[l*NWAVE+w];
          s += e*gs[w];
          q += e*tw[w];
        }
        sl[l] = s;
        radial += mono[l]*q;
      }
      float Ax = sl[1] + 2.f*sl[4]*dx + (sl[5]+sl[7])*dy + (sl[6]+sl[10])*dz;
      float Ay = sl[2] + (sl[5]+sl[7])*dx + 2.f*sl[8]*dy + (sl[9]+sl[11])*dz;
      float Az = sl[3] + (sl[6]+sl[10])*dx + (sl[9]+sl[11])*dy + 2.f*sl[12]*dz;
      float rr = radial*invd;
      float fx = dx*rr + fc*Ax;
      float fy = dy*rr + fc*Ay;
      float fz = dz*rr + fc*Az;
      if(net==0){ f1[0]=fx; f1[1]=fy; f1[2]=fz; }
      else      { f2[0]=fx; f2[1]=fy; f2[2]=fz; }
    }
    // cart[i]-cart[j] = dvec - shift ;  P += (cart_i - cart_j) (x) f1
    float cx = dx-shx, cy = dy-shy, cz = dz-shz;
    p[0]=cx*f1[0]; p[1]=cx*f1[1]; p[2]=cx*f1[2];
    p[3]=cy*f1[0]; p[4]=cy*f1[1]; p[5]=cy*f1[2];
    p[6]=cz*f1[0]; p[7]=cz*f1[1]; p[8]=cz*f1[2];
    // per-pair neighbor force (gathered by scatter_kernel in LDS)
    float* fb = f2buf + (size_t)m*3;
    fb[0]=f2[0]; fb[1]=f2[1]; fb[2]=f2[2];
    fi2[0]=f2[0]; fi2[1]=f2[1]; fi2[2]=f2[2];
  }
  #pragma unroll
  for(int k=0;k<9;k++){
    float v = wave_reduce(p[k]);
    if(t==0) Ppart[(size_t)i*9+k] = v;
  }
  #pragma unroll
  for(int c=0;c<3;c++){
    float v = wave_reduce(fi2[c]);
    if(t==0) jab2c[(size_t)i*3+c] = v;
  }
}

// ---------------- K5: LDS-privatized scatter of -f2 onto neighbor atoms ---------
__global__ void scatter_kernel(const int* __restrict__ neighJ, const float* __restrict__ f2buf,
                               float* __restrict__ jpart, int M, int N){
  __shared__ float lds[NMAX];
  int b = blockIdx.x, t = threadIdx.x;
  int chunk = (M + gridDim.x - 1) / gridDim.x;
  int m0 = b*chunk;
  int m1 = m0 + chunk; if(m1 > M) m1 = M;
  for(int c=0;c<3;c++){
    for(int n=t; n<N; n+=256) lds[n] = 0.f;
    __syncthreads();
    for(int m=m0+t; m<m1; m+=256)
      atomicAdd(&lds[neighJ[m]], -f2buf[(size_t)m*3+c]);
    __syncthreads();
    float* dst = jpart + ((size_t)b*3 + c)*N;
    for(int n=t; n<N; n+=256) dst[n] = lds[n];
    __syncthreads();
  }
}

// ---------------- K6: jab2 total -> S2 partials; Ppart -> P sum ------------------
__global__ void reduce_kernel(const float* __restrict__ Ppart, const float* __restrict__ jab2c,
                              const float* __restrict__ jpart,
                              float* __restrict__ Pacc, float* __restrict__ S2, int N){
  __shared__ float red[256];
  int tid = threadIdx.x;
  float s2[9] = {0.f,0.f,0.f,0.f,0.f,0.f,0.f,0.f,0.f};
  float pp[9] = {0.f,0.f,0.f,0.f,0.f,0.f,0.f,0.f,0.f};
  for(int n = blockIdx.x*256 + tid; n < N; n += gridDim.x*256){
    float x = jab2c[n*3+0], y = jab2c[n*3+1], z = jab2c[n*3+2];
    for(int b=0;b<NBSC;b++){
      const float* jp = jpart + (size_t)b*3*N;
      x += jp[0*(size_t)N + n];
      y += jp[1*(size_t)N + n];
      z += jp[2*(size_t)N + n];
    }
    s2[0]+=x*x; s2[1]+=x*y; s2[2]+=x*z;
    s2[3]+=y*x; s2[4]+=y*y; s2[5]+=y*z;
    s2[6]+=z*x; s2[7]+=z*y; s2[8]+=z*z;
    const float* pr = Ppart + (size_t)n*9;
    #pragma unroll
    for(int k=0;k<9;k++) pp[k] += pr[k];
  }
  #pragma unroll
  for(int k=0;k<9;k++){
    red[tid]=s2[k]; __syncthreads();
    for(int off=128; off>0; off>>=1){
      if(tid<off) red[tid]+=red[tid+off];
      __syncthreads();
    }
    if(tid==0) atomicAdd(&S2[k], red[0]);
    __syncthreads();
    red[tid]=pp[k]; __syncthreads();
    for(int off=128; off>0; off>>=1){
      if(tid<off) red[tid]+=red[tid+off];
      __syncthreads();
    }
    if(tid==0) atomicAdd(&Pacc[k], red[0]);
    __syncthreads();
  }
}

// ---------------- K7: assemble --------------------------------------------------
__global__ void final_kernel(const float* __restrict__ Pacc, const float* __restrict__ S2,
                             const float* __restrict__ e2acc, float* __restrict__ out){
  int tid = threadIdx.x;
  if(tid < 9){
    int a = tid/3, b = tid%3;
    float v = Pacc[a*3+b] + Pacc[b*3+a] + S2[tid];
    if(a==b) v += e2acc[0];
    out[tid] = v;
  }
}

extern "C" void kernel_launch(void* const* d_in, const int* in_sizes, int n_in,
                              void* d_out, int out_size, void* d_ws, size_t ws_size,
                              hipStream_t stream){
  const float* cart    = (const float*)d_in[0];
  const float* shifts  = (const float*)d_in[1];
  const float* rs      = (const float*)d_in[2];
  const float* inta    = (const float*)d_in[3];
  const float* cparams = (const float*)d_in[4];
  const float* w1 = (const float*)d_in[5];
  const float* b1 = (const float*)d_in[6];
  const float* a1 = (const float*)d_in[7];
  const float* g1 = (const float*)d_in[8];
  const float* w2 = (const float*)d_in[9];
  const float* b2 = (const float*)d_in[10];
  const float* a2 = (const float*)d_in[11];
  const float* g2 = (const float*)d_in[12];
  const float* w3 = (const float*)d_in[13];
  const float* b3 = (const float*)d_in[14];
  const float* a3 = (const float*)d_in[15];
  const float* g3 = (const float*)d_in[16];
  const float* w4 = (const float*)d_in[17];
  const float* b4 = (const float*)d_in[18];
  const float* a4 = (const float*)d_in[19];
  const float* g4 = (const float*)d_in[20];
  const float* wout = (const float*)d_in[21];
  const float* bout = (const float*)d_in[22];
  const int* species = (const int*)d_in[23];
  const int* neigh   = (const int*)d_in[24];
  float* out = (float*)d_out;

  const int N = in_sizes[0]/3;
  const int M = in_sizes[24]/2;
  const int K = M/N;
  const int* neighJ = neigh + M;

  char* base = (char*)d_ws;
  size_t off = 0;
  auto alloc = [&](size_t bytes)->void*{
    void* p = base + off;
    off = (off + bytes + 255) & ~(size_t)255;
    return p;
  };
  float*  Bws    = (float*)alloc((size_t)N*NBW*4);
  float*  G1ws   = (float*)alloc((size_t)N*D0*4);
  float*  G2ws   = (float*)alloc((size_t)N*D0*4);
  float*  Ppart  = (float*)alloc((size_t)N*9*4);
  float*  jab2c  = (float*)alloc((size_t)N*3*4);
  float*  f2buf  = (float*)alloc((size_t)M*3*4);
  float4* pairbuf= (float4*)alloc((size_t)M*16);
  float*  jpart  = (float*)alloc((size_t)NBSC*3*N*4);
  float*  acc    = (float*)alloc(32*4);          // P[0..8], S2[9..17], e2[18]
  int*    counts = (int*)alloc(2*4);
  int*    perm   = (int*)alloc((size_t)2*N*4);
  float*  WT1    = (float*)alloc((size_t)6*D0*D1*4);
  float*  WT2    = (float*)alloc((size_t)6*D1*D2*4);
  float*  WT3    = (float*)alloc((size_t)6*D2*D3*4);
  float*  WT4    = (float*)alloc((size_t)6*D3*D4*4);

  hipMemsetAsync(acc, 0, 32*4, stream);

  // allow >64KB dynamic LDS for pairs_kernel (160KB/CU on gfx950)
  size_t ldsBytes = (size_t)N*16;
  hipFuncSetAttribute((const void*)pairs_kernel,
                      hipFuncAttributeMaxDynamicSharedMemorySize, (int)ldsBytes);

  const int ETOT = 6*(D0*D1 + D1*D2 + D2*D3 + D3*D4);
  perm_kernel<<<1,256,0,stream>>>(species, perm, counts, N);
  transpose_all_kernel<<<(ETOT+255)/256,256,0,stream>>>(w1,w2,w3,w4, WT1,WT2,WT3,WT4);
  pairs_kernel<<<256,1024,ldsBytes,stream>>>(cart, shifts, species, neighJ, pairbuf, M, N, K);
  density_kernel<<<N,64,0,stream>>>(pairbuf, rs, inta, cparams, Bws, K);
  mlp_kernel<<<3*2*(N/AT),256,0,stream>>>(Bws, perm, counts,
      w1,b1,a1,g1, w2,b2,a2,g2, w3,b3,a3,g3, w4,b4,a4,g4, wout,bout,
      WT1,WT2,WT3,WT4, G1ws,G2ws, acc+18, N);
  pair_back_kernel<<<N,64,0,stream>>>(pairbuf, shifts, rs, inta, cparams,
                                      Bws, G1ws, G2ws, Ppart, jab2c, f2buf, K);
  scatter_kernel<<<NBSC,256,0,stream>>>(neighJ, f2buf, jpart, M, N);
  reduce_kernel<<<64,256,0,stream>>>(Ppart, jab2c, jpart, acc, acc+9, N);
  final_kernel<<<1,64,0,stream>>>(acc, acc+9, acc+18, out);
}

// Round 15
// 284.944 us; speedup vs baseline: 1.4823x; 1.4061x over previous
//
#include <hip/hip_runtime.h>

#define NWAVE 12
#define NL 13
#define NBW (NL*NWAVE)   // 156
#define D0 36
#define D1 256
#define D2 128
#define D3 64
#define D4 32
#define AT 16            // atoms per MLP block (R12 optimum)
#define NMAX 8192
#define NBSC 128         // scatter privatization blocks
#define PI6 0.52359877559829887307f

#define F4(p) (*(const float4*)(p))
#define F2(p) (*(const float2*)(p))

__device__ __forceinline__ float wave_reduce(float v){
  #pragma unroll
  for(int o=32;o>0;o>>=1) v += __shfl_down(v,o);
  return v;
}

// ---------------- perm: stable partition of atoms by species (deterministic) ----
__global__ void perm_kernel(const int* __restrict__ species, int* __restrict__ perm,
                            int* __restrict__ counts, int N){
  __shared__ int sc[256];
  int t = threadIdx.x;
  int per = N/256;
  int c0 = 0;
  for(int k=0;k<per;k++) c0 += (species[t*per+k]==0) ? 1 : 0;
  sc[t]=c0; __syncthreads();
  for(int off=1; off<256; off<<=1){
    int add = (t>=off)? sc[t-off] : 0;
    __syncthreads();
    sc[t] += add;
    __syncthreads();
  }
  int incl = sc[t];
  int excl = incl - c0;
  int total0 = sc[255];
  if(t==0){ counts[0]=total0; counts[1]=N-total0; }
  int base0 = excl;
  int base1 = N + (t*per - excl);
  for(int k=0;k<per;k++){
    int a = t*per+k;
    if(species[a]==0) perm[base0++]=a; else perm[base1++]=a;
  }
}

// ---------------- fused weight transpose (one launch for all 4 layers) ----------
__global__ void transpose_all_kernel(const float* __restrict__ w1, const float* __restrict__ w2,
                                     const float* __restrict__ w3, const float* __restrict__ w4,
                                     float* __restrict__ t1, float* __restrict__ t2,
                                     float* __restrict__ t3, float* __restrict__ t4){
  const int E1 = 6*D0*D1, E2 = 6*D1*D2, E3 = 6*D2*D3, E4 = 6*D3*D4;
  int idx = blockIdx.x*256 + threadIdx.x;
  if(idx < E1){
    int slab = idx/(D0*D1), r = idx%(D0*D1);
    int f = r/D1, o = r%D1;
    t1[slab*D0*D1 + o*D0 + f] = w1[idx];
  } else if(idx < E1+E2){
    int k = idx-E1; int slab = k/(D1*D2), r = k%(D1*D2);
    int f = r/D2, o = r%D2;
    t2[slab*D1*D2 + o*D1 + f] = w2[k];
  } else if(idx < E1+E2+E3){
    int k = idx-E1-E2; int slab = k/(D2*D3), r = k%(D2*D3);
    int f = r/D3, o = r%D3;
    t3[slab*D2*D3 + o*D2 + f] = w3[k];
  } else if(idx < E1+E2+E3+E4){
    int k = idx-E1-E2-E3; int slab = k/(D3*D4), r = k%(D3*D4);
    int f = r/D4, o = r%D4;
    t4[slab*D3*D4 + o*D3 + f] = w4[k];
  }
}

// ---------------- K0: per-pair geometry via LDS-resident cart -------------------
__global__ void pairs_kernel(const float* __restrict__ cart, const float* __restrict__ shifts,
                             const int* __restrict__ species, const int* __restrict__ neighJ,
                             float4* __restrict__ pairbuf, int M, int N, int K){
  extern __shared__ float4 ca[];
  int t = threadIdx.x;
  for(int a=t; a<N; a+=blockDim.x)
    ca[a] = make_float4(cart[a*3+0], cart[a*3+1], cart[a*3+2], (float)species[a]);
  __syncthreads();
  int stride = gridDim.x*blockDim.x;
  for(int m = blockIdx.x*blockDim.x + t; m < M; m += stride){
    int i = m / K;
    int j = neighJ[m];
    float4 cj = ca[j];
    float4 ci = ca[i];
    float dx = ci.x - cj.x + shifts[m*3+0];
    float dy = ci.y - cj.y + shifts[m*3+1];
    float dz = ci.z - cj.z + shifts[m*3+2];
    float dist = sqrtf(dx*dx+dy*dy+dz*dz);
    float enc = (cj.w != 0.f) ? -dist : dist;
    pairbuf[m] = make_float4(dx, dy, dz, enc);
  }
}

// ---------------- K1: B[n,13,12]; 4 waves/block, one atom per wave --------------
__launch_bounds__(256, 1)
__global__ void density_kernel(const float4* __restrict__ pairbuf,
                               const float* __restrict__ rs, const float* __restrict__ inta,
                               const float* __restrict__ cparams,
                               float* __restrict__ B, int K){
  int wv = threadIdx.x >> 6;
  int t  = threadIdx.x & 63;
  int i  = blockIdx.x*4 + wv;
  __shared__ float sang[4][64][NL];
  __shared__ float sg[4][64][NWAVE];
  if(t < K){
    float4 pb = pairbuf[(size_t)i*K + t];
    float dx = pb.x, dy = pb.y, dz = pb.z;
    int sj = (pb.w < 0.f) ? 1 : 0;
    float dist = fabsf(pb.w);
    float base = 0.5f*cosf(dist*PI6)+0.5f;
    float fc = base*base;
    #pragma unroll
    for(int w=0;w<NWAVE;w++){
      float d = dist - rs[sj*NWAVE+w];
      sg[wv][t][w] = __expf(inta[sj*NWAVE+w]*d*d)*cparams[sj*NWAVE+w];
    }
    sang[wv][t][0]=fc;
    sang[wv][t][1]=fc*dx;  sang[wv][t][2]=fc*dy;  sang[wv][t][3]=fc*dz;
    sang[wv][t][4]=fc*dx*dx; sang[wv][t][5]=fc*dx*dy; sang[wv][t][6]=fc*dx*dz;
    sang[wv][t][7]=fc*dy*dx; sang[wv][t][8]=fc*dy*dy; sang[wv][t][9]=fc*dy*dz;
    sang[wv][t][10]=fc*dz*dx; sang[wv][t][11]=fc*dz*dy; sang[wv][t][12]=fc*dz*dz;
  }
  __syncthreads();
  for(int idx=t; idx<NBW; idx+=64){
    int l = idx/NWAVE, w = idx%NWAVE;
    float s = 0.f;
    for(int k=0;k<K;k++) s += sang[wv][k][l]*sg[wv][k][w];
    B[(size_t)i*NBW+idx] = s;
  }
}

// ---------------- K3: per-(net,type,atom-group) MLP fwd + bwd (R12 optimum) -----
// AT=16, multi-col register tiling (4x4/4x2/2x2/2x1), net-split grid,
// launch_bounds(256,1): no VGPR cap -> no spill (VGPR 128). Best measured: 181us.
__launch_bounds__(256, 1)
__global__ void mlp_kernel(const float* __restrict__ B,
    const int* __restrict__ perm, const int* __restrict__ counts,
    const float* __restrict__ w1,const float* __restrict__ b1,const float* __restrict__ a1,const float* __restrict__ g1,
    const float* __restrict__ w2,const float* __restrict__ b2,const float* __restrict__ a2,const float* __restrict__ g2,
    const float* __restrict__ w3,const float* __restrict__ b3,const float* __restrict__ a3,const float* __restrict__ g3,
    const float* __restrict__ w4,const float* __restrict__ b4,const float* __restrict__ a4,const float* __restrict__ g4,
    const float* __restrict__ wout,const float* __restrict__ bout,
    const float* __restrict__ wt1,const float* __restrict__ wt2,const float* __restrict__ wt3,const float* __restrict__ wt4,
    float* __restrict__ G1, float* __restrict__ G2, float* __restrict__ e2acc, int N)
{
  const int bpt = N/AT;
  const int net = blockIdx.x / (2*bpt);
  const int rem = blockIdx.x % (2*bpt);
  const int typ = rem / bpt;
  const int sbase = (rem % bpt)*AT;
  const int cnt = counts[typ];
  if(sbase >= cnt) return;
  const int tid = threadIdx.x;
  const int slab = net*2 + typ;

  __shared__ __align__(16) float X[AT][D0];
  __shared__ __align__(16) float H1s[AT*D1];   // also dz3 [AT][64] then dz1 [AT][256]
  __shared__ __align__(16) float H2s[AT*D2];   // also dz2 [AT][128]
  __shared__ __align__(16) float H3s[AT*D3];   // also dz4 [AT][32]
  __shared__ __align__(16) float H4s[AT*D4];
  __shared__ int atomsS[AT];

  if(tid < AT){
    int slot = sbase + tid;
    atomsS[tid] = (slot < cnt) ? perm[typ*N + slot] : -1;
  }
  __syncthreads();

  // density features
  for(int idx=tid; idx<AT*D0; idx+=256){
    int r = idx/D0, f = idx%D0;
    int a = atomsS[r];
    float v = 0.f;
    if(a >= 0){
      int w = f%NWAVE, grp = f/NWAVE;
      const float* Br = B + a*NBW;
      if(grp==0){ float b0=Br[w]; v=b0*b0; }
      else if(grp==1){
        #pragma unroll
        for(int l=1;l<4;l++){ float b0=Br[l*NWAVE+w]; v += b0*b0; }
      } else {
        #pragma unroll
        for(int l=4;l<13;l++){ float b0=Br[l*NWAVE+w]; v += b0*b0; }
      }
    }
    X[r][f] = v;
  }
  __syncthreads();

  // thread-ownership maps (same in fwd and bwd per layer)
  const int l1c = (tid & 63)*4,  l1r = (tid >> 6)*4;   // L1/dz1: 4r x 4c
  const int l2c = (tid & 63)*2,  l2r = (tid >> 6)*4;   // L2/dz2: 4r x 2c
  const int l3c = (tid & 31)*2,  l3r = (tid >> 5)*2;   // L3/dz3: 2r x 2c
  const int l4c = (tid & 31),    l4r = (tid >> 5)*2;   // L4/dz4: 2r x 1c

  // persistent activation-derivative registers (live fwd -> bwd)
  float A1r[4][4], A2r[4][2], A3r[2][2], A4r[2];

  // ---- L1: 36 -> 256, tile 4x4
  {
    const float* W = w1 + slab*D0*D1;
    float acc[4][4];
    {
      float4 bv = F4(&b1[slab*D1+l1c]);
      #pragma unroll
      for(int rr=0;rr<4;rr++){ acc[rr][0]=bv.x; acc[rr][1]=bv.y; acc[rr][2]=bv.z; acc[rr][3]=bv.w; }
    }
    #pragma unroll
    for(int kk=0; kk<D0/4; kk++){
      float4 wa = F4(&W[(kk*4+0)*D1+l1c]);
      float4 wb = F4(&W[(kk*4+1)*D1+l1c]);
      float4 wc = F4(&W[(kk*4+2)*D1+l1c]);
      float4 wd = F4(&W[(kk*4+3)*D1+l1c]);
      #pragma unroll
      for(int rr=0;rr<4;rr++){
        float4 xv = F4(&X[l1r+rr][kk*4]);
        acc[rr][0] += xv.x*wa.x + xv.y*wb.x + xv.z*wc.x + xv.w*wd.x;
        acc[rr][1] += xv.x*wa.y + xv.y*wb.y + xv.z*wc.y + xv.w*wd.y;
        acc[rr][2] += xv.x*wa.z + xv.y*wb.z + xv.z*wc.z + xv.w*wd.z;
        acc[rr][3] += xv.x*wa.w + xv.y*wb.w + xv.z*wc.w + xv.w*wd.w;
      }
    }
    float4 av4 = F4(&a1[slab*D1+l1c]);
    float4 gv4 = F4(&g1[slab*D1+l1c]);
    float avv[4] = {av4.x, av4.y, av4.z, av4.w};
    float gvv[4] = {gv4.x, gv4.y, gv4.z, gv4.w};
    #pragma unroll
    for(int rr=0;rr<4;rr++){
      float hp[4];
      #pragma unroll
      for(int cc=0;cc<4;cc++){
        float u = gvv[cc]*acc[rr][cc];
        float s = 1.f/(1.f+__expf(-u));
        hp[cc] = avv[cc]*u*s;
        A1r[rr][cc] = avv[cc]*gvv[cc]*s*(1.f + u*(1.f-s));
      }
      float4 h; h.x=hp[0]; h.y=hp[1]; h.z=hp[2]; h.w=hp[3];
      *(float4*)&H1s[(l1r+rr)*D1 + l1c] = h;
    }
  }
  __syncthreads();
  // ---- L2: 256 -> 128, tile 4x2
  {
    const float* W = w2 + slab*D1*D2;
    float acc[4][2];
    {
      float2 bv = F2(&b2[slab*D2+l2c]);
      #pragma unroll
      for(int rr=0;rr<4;rr++){ acc[rr][0]=bv.x; acc[rr][1]=bv.y; }
    }
    for(int kk=0; kk<D1/4; kk++){
      float2 wa = F2(&W[(kk*4+0)*D2+l2c]);
      float2 wb = F2(&W[(kk*4+1)*D2+l2c]);
      float2 wc = F2(&W[(kk*4+2)*D2+l2c]);
      float2 wd = F2(&W[(kk*4+3)*D2+l2c]);
      #pragma unroll
      for(int rr=0;rr<4;rr++){
        float4 hv = F4(&H1s[(l2r+rr)*D1 + kk*4]);
        acc[rr][0] += hv.x*wa.x + hv.y*wb.x + hv.z*wc.x + hv.w*wd.x;
        acc[rr][1] += hv.x*wa.y + hv.y*wb.y + hv.z*wc.y + hv.w*wd.y;
      }
    }
    float2 av2 = F2(&a2[slab*D2+l2c]);
    float2 gv2 = F2(&g2[slab*D2+l2c]);
    float avv[2] = {av2.x, av2.y};
    float gvv[2] = {gv2.x, gv2.y};
    #pragma unroll
    for(int rr=0;rr<4;rr++){
      float hp[2];
      #pragma unroll
      for(int cc=0;cc<2;cc++){
        float u = gvv[cc]*acc[rr][cc];
        float s = 1.f/(1.f+__expf(-u));
        hp[cc] = avv[cc]*u*s;
        A2r[rr][cc] = avv[cc]*gvv[cc]*s*(1.f + u*(1.f-s));
      }
      float2 h; h.x=hp[0]; h.y=hp[1];
      *(float2*)&H2s[(l2r+rr)*D2 + l2c] = h;
    }
  }
  __syncthreads();
  // ---- L3: 128 -> 64, tile 2x2
  {
    const float* W = w3 + slab*D2*D3;
    float acc[2][2];
    {
      float2 bv = F2(&b3[slab*D3+l3c]);
      #pragma unroll
      for(int rr=0;rr<2;rr++){ acc[rr][0]=bv.x; acc[rr][1]=bv.y; }
    }
    for(int kk=0; kk<D2/4; kk++){
      float2 wa = F2(&W[(kk*4+0)*D3+l3c]);
      float2 wb = F2(&W[(kk*4+1)*D3+l3c]);
      float2 wc = F2(&W[(kk*4+2)*D3+l3c]);
      float2 wd = F2(&W[(kk*4+3)*D3+l3c]);
      #pragma unroll
      for(int rr=0;rr<2;rr++){
        float4 hv = F4(&H2s[(l3r+rr)*D2 + kk*4]);
        acc[rr][0] += hv.x*wa.x + hv.y*wb.x + hv.z*wc.x + hv.w*wd.x;
        acc[rr][1] += hv.x*wa.y + hv.y*wb.y + hv.z*wc.y + hv.w*wd.y;
      }
    }
    float2 av2 = F2(&a3[slab*D3+l3c]);
    float2 gv2 = F2(&g3[slab*D3+l3c]);
    float avv[2] = {av2.x, av2.y};
    float gvv[2] = {gv2.x, gv2.y};
    #pragma unroll
    for(int rr=0;rr<2;rr++){
      float hp[2];
      #pragma unroll
      for(int cc=0;cc<2;cc++){
        float u = gvv[cc]*acc[rr][cc];
        float s = 1.f/(1.f+__expf(-u));
        hp[cc] = avv[cc]*u*s;
        A3r[rr][cc] = avv[cc]*gvv[cc]*s*(1.f + u*(1.f-s));
      }
      float2 h; h.x=hp[0]; h.y=hp[1];
      *(float2*)&H3s[(l3r+rr)*D3 + l3c] = h;
    }
  }
  __syncthreads();
  // ---- L4: 64 -> 32, tile 2x1
  {
    const float* W = w4 + slab*D3*D4;
    float bias = b4[slab*D4+l4c];
    float acc[2] = {bias, bias};
    for(int kk=0; kk<D3/4; kk++){
      float wa = W[(kk*4+0)*D4+l4c];
      float wb = W[(kk*4+1)*D4+l4c];
      float wc = W[(kk*4+2)*D4+l4c];
      float wd = W[(kk*4+3)*D4+l4c];
      #pragma unroll
      for(int rr=0;rr<2;rr++){
        float4 hv = F4(&H3s[(l4r+rr)*D3 + kk*4]);
        acc[rr] += hv.x*wa + hv.y*wb + hv.z*wc + hv.w*wd;
      }
    }
    float av = a4[slab*D4+l4c], gv = g4[slab*D4+l4c];
    #pragma unroll
    for(int rr=0;rr<2;rr++){
      float u = gv*acc[rr];
      float s = 1.f/(1.f+__expf(-u));
      H4s[(l4r+rr)*D4+l4c] = av*u*s;
      A4r[rr] = av*gv*s*(1.f + u*(1.f-s));
    }
  }
  __syncthreads();
  // ---- output layer (+ e2 for net 2)
  {
    const float* wo = wout + slab*D4;
    float val = 0.f;
    if(tid < AT){
      float s = bout[slab];
      const float* hr = &H4s[tid*D4];
      #pragma unroll
      for(int f=0;f<D4;f++) s += hr[f]*wo[f];
      if(net==2 && atomsS[tid]>=0) val = s;
    }
    if(net==2 && tid < 64){
      float v = wave_reduce(val);
      if(tid==0) atomicAdd(e2acc, v);
    }
  }
  // ---- backward for nets 0,1: G = dE/ddensity
  if(net < 2){
    float* __restrict__ Gout = (net==0)? G1 : G2;
    const float* wo = wout + slab*D4;
    __syncthreads();
    // dz4 -> H3s as [AT][32]   (ownership = L4 map)
    {
      float wv = wo[l4c];
      H3s[(l4r+0)*D4+l4c] = wv * A4r[0];
      H3s[(l4r+1)*D4+l4c] = wv * A4r[1];
    }
    __syncthreads();
    // dz3 = (dz4 @ W4^T)*A3 -> H1s as [AT][64]  (ownership = L3 map)
    {
      const float* WT = wt4 + slab*D4*D3;   // [32][64]
      float acc[2][2] = {{0.f,0.f},{0.f,0.f}};
      #pragma unroll
      for(int kk=0; kk<D4/4; kk++){
        float2 wa = F2(&WT[(kk*4+0)*D3+l3c]);
        float2 wb = F2(&WT[(kk*4+1)*D3+l3c]);
        float2 wc = F2(&WT[(kk*4+2)*D3+l3c]);
        float2 wd = F2(&WT[(kk*4+3)*D3+l3c]);
        #pragma unroll
        for(int rr=0;rr<2;rr++){
          float4 dv = F4(&H3s[(l3r+rr)*D4 + kk*4]);
          acc[rr][0] += dv.x*wa.x + dv.y*wb.x + dv.z*wc.x + dv.w*wd.x;
          acc[rr][1] += dv.x*wa.y + dv.y*wb.y + dv.z*wc.y + dv.w*wd.y;
        }
      }
      #pragma unroll
      for(int rr=0;rr<2;rr++){
        float2 h;
        h.x = acc[rr][0]*A3r[rr][0];
        h.y = acc[rr][1]*A3r[rr][1];
        *(float2*)&H1s[(l3r+rr)*D3 + l3c] = h;
      }
    }
    __syncthreads();
    // dz2 = (dz3 @ W3^T)*A2 -> H2s as [AT][128]  (ownership = L2 map)
    {
      const float* WT = wt3 + slab*D3*D2;   // [64][128]
      float acc[4][2] = {{0.f,0.f},{0.f,0.f},{0.f,0.f},{0.f,0.f}};
      for(int kk=0; kk<D3/4; kk++){
        float2 wa = F2(&WT[(kk*4+0)*D2+l2c]);
        float2 wb = F2(&WT[(kk*4+1)*D2+l2c]);
        float2 wc = F2(&WT[(kk*4+2)*D2+l2c]);
        float2 wd = F2(&WT[(kk*4+3)*D2+l2c]);
        #pragma unroll
        for(int rr=0;rr<4;rr++){
          float4 dv = F4(&H1s[(l2r+rr)*D3 + kk*4]);
          acc[rr][0] += dv.x*wa.x + dv.y*wb.x + dv.z*wc.x + dv.w*wd.x;
          acc[rr][1] += dv.x*wa.y + dv.y*wb.y + dv.z*wc.y + dv.w*wd.y;
        }
      }
      #pragma unroll
      for(int rr=0;rr<4;rr++){
        float2 h;
        h.x = acc[rr][0]*A2r[rr][0];
        h.y = acc[rr][1]*A2r[rr][1];
        *(float2*)&H2s[(l2r+rr)*D2 + l2c] = h;
      }
    }
    __syncthreads();
    // dz1 = (dz2 @ W2^T)*A1 -> H1s as [AT][256]  (ownership = L1 map)
    {
      const float* WT = wt2 + slab*D2*D1;   // [128][256]
      float acc[4][4];
      #pragma unroll
      for(int rr=0;rr<4;rr++){ acc[rr][0]=0.f; acc[rr][1]=0.f; acc[rr][2]=0.f; acc[rr][3]=0.f; }
      for(int kk=0; kk<D2/4; kk++){
        float4 wa = F4(&WT[(kk*4+0)*D1+l1c]);
        float4 wb = F4(&WT[(kk*4+1)*D1+l1c]);
        float4 wc = F4(&WT[(kk*4+2)*D1+l1c]);
        float4 wd = F4(&WT[(kk*4+3)*D1+l1c]);
        #pragma unroll
        for(int rr=0;rr<4;rr++){
          float4 dv = F4(&H2s[(l1r+rr)*D2 + kk*4]);
          acc[rr][0] += dv.x*wa.x + dv.y*wb.x + dv.z*wc.x + dv.w*wd.x;
          acc[rr][1] += dv.x*wa.y + dv.y*wb.y + dv.z*wc.y + dv.w*wd.y;
          acc[rr][2] += dv.x*wa.z + dv.y*wb.z + dv.z*wc.z + dv.w*wd.z;
          acc[rr][3] += dv.x*wa.w + dv.y*wb.w + dv.z*wc.w + dv.w*wd.w;
        }
      }
      #pragma unroll
      for(int rr=0;rr<4;rr++){
        float4 h;
        h.x = acc[rr][0]*A1r[rr][0];
        h.y = acc[rr][1]*A1r[rr][1];
        h.z = acc[rr][2]*A1r[rr][2];
        h.w = acc[rr][3]*A1r[rr][3];
        *(float4*)&H1s[(l1r+rr)*D1 + l1c] = h;
      }
    }
    __syncthreads();
    // G = dz1 @ W1^T  (36 outputs per row)
    {
      const float* WT = wt1 + slab*D1*D0;
      for(int idx=tid; idx<AT*D0; idx+=256){
        int r = idx/D0, f = idx%D0;
        const float* dr = &H1s[r*D1];
        float acc = 0.f;
        for(int oo=0; oo<D1; oo+=4){
          const float4 dv = F4(&dr[oo]);
          acc += dv.x*WT[(oo+0)*D0+f] + dv.y*WT[(oo+1)*D0+f]
               + dv.z*WT[(oo+2)*D0+f] + dv.w*WT[(oo+3)*D0+f];
        }
        int a = atomsS[r];
        if(a >= 0) Gout[a*D0+f] = acc;
      }
    }
  }
}

// ---------------- K4: per-pair backward; 4 waves/block, one atom per wave -------
__launch_bounds__(256, 1)
__global__ void pair_back_kernel(const float4* __restrict__ pairbuf,
                                 const float* __restrict__ shifts,
                                 const float* __restrict__ rs, const float* __restrict__ inta,
                                 const float* __restrict__ cparams,
                                 const float* __restrict__ B,
                                 const float* __restrict__ G1, const float* __restrict__ G2,
                                 float* __restrict__ Ppart, float* __restrict__ jab2c,
                                 float* __restrict__ f2buf, int K){
  int wv = threadIdx.x >> 6;
  int t  = threadIdx.x & 63;
  int i  = blockIdx.x*4 + wv;
  __shared__ float E1[4][NBW], E2[4][NBW];
  for(int idx=t; idx<NBW; idx+=64){
    int l = idx/NWAVE, w = idx%NWAVE;
    int grp = (l==0) ? 0 : ((l<4) ? 1 : 2);
    float b = B[(size_t)i*NBW+idx];
    E1[wv][idx] = 2.f*b*G1[(size_t)i*D0 + grp*NWAVE + w];
    E2[wv][idx] = 2.f*b*G2[(size_t)i*D0 + grp*NWAVE + w];
  }
  __syncthreads();
  float p[9] = {0.f,0.f,0.f,0.f,0.f,0.f,0.f,0.f,0.f};
  float fi2[3] = {0.f,0.f,0.f};
  if(t < K){
    int m = i*K + t;
    float4 pb = pairbuf[(size_t)m];
    float dx = pb.x, dy = pb.y, dz = pb.z;
    int sj = (pb.w < 0.f) ? 1 : 0;
    float dist = fabsf(pb.w);
    float shx = shifts[m*3+0], shy = shifts[m*3+1], shz = shifts[m*3+2];
    float invd = 1.f/dist;
    float u = dist*PI6;
    float base = 0.5f*cosf(u)+0.5f;
    float fc = base*base;
    float fcp = -PI6*sinf(u)*base;      // d fc / d dist
    float gs[NWAVE], tw[NWAVE];
    #pragma unroll
    for(int w=0;w<NWAVE;w++){
      float d = dist - rs[sj*NWAVE+w];
      float ia = inta[sj*NWAVE+w];
      float g = __expf(ia*d*d)*cparams[sj*NWAVE+w];
      gs[w] = g;
      tw[w] = fcp*g + fc*(2.f*ia*d*g);  // d(fc*gauss)/d dist factor
    }
    float mono[NL] = {1.f, dx,dy,dz, dx*dx,dx*dy,dx*dz, dy*dx,dy*dy,dy*dz, dz*dx,dz*dy,dz*dz};
    float f1[3], f2[3];
    for(int net=0; net<2; net++){
      const float* E = net ? E2[wv] : E1[wv];
      float sl[NL];
      float radial = 0.f;
      #pragma unroll
      for(int l=0;l<NL;l++){
        float s = 0.f, q = 0.f;
        #pragma unroll
        for(int w=0;w<NWAVE;w++){
          float e = E[l*NWAVE+w];
          s += e*gs[w];
          q += e*tw[w];
        }
        sl[l] = s;
        radial += mono[l]*q;
      }
      float Ax = sl[1] + 2.f*sl[4]*dx + (sl[5]+sl[7])*dy + (sl[6]+sl[10])*dz;
      float Ay = sl[2] + (sl[5]+sl[7])*dx + 2.f*sl[8]*dy + (sl[9]+sl[11])*dz;
      float Az = sl[3] + (sl[6]+sl[10])*dx + (sl[9]+sl[11])*dy + 2.f*sl[12]*dz;
      float rr = radial*invd;
      float fx = dx*rr + fc*Ax;
      float fy = dy*rr + fc*Ay;
      float fz = dz*rr + fc*Az;
      if(net==0){ f1[0]=fx; f1[1]=fy; f1[2]=fz; }
      else      { f2[0]=fx; f2[1]=fy; f2[2]=fz; }
    }
    // cart[i]-cart[j] = dvec - shift ;  P += (cart_i - cart_j) (x) f1
    float cx = dx-shx, cy = dy-shy, cz = dz-shz;
    p[0]=cx*f1[0]; p[1]=cx*f1[1]; p[2]=cx*f1[2];
    p[3]=cy*f1[0]; p[4]=cy*f1[1]; p[5]=cy*f1[2];
    p[6]=cz*f1[0]; p[7]=cz*f1[1]; p[8]=cz*f1[2];
    // per-pair neighbor force (gathered by scatter_kernel in LDS)
    float* fb = f2buf + (size_t)m*3;
    fb[0]=f2[0]; fb[1]=f2[1]; fb[2]=f2[2];
    fi2[0]=f2[0]; fi2[1]=f2[1]; fi2[2]=f2[2];
  }
  #pragma unroll
  for(int k=0;k<9;k++){
    float v = wave_reduce(p[k]);
    if(t==0) Ppart[(size_t)i*9+k] = v;
  }
  #pragma unroll
  for(int c=0;c<3;c++){
    float v = wave_reduce(fi2[c]);
    if(t==0) jab2c[(size_t)i*3+c] = v;
  }
}

// ---------------- K5: LDS-privatized scatter of -f2 onto neighbor atoms ---------
__global__ void scatter_kernel(const int* __restrict__ neighJ, const float* __restrict__ f2buf,
                               float* __restrict__ jpart, int M, int N){
  __shared__ float lds[NMAX];
  int b = blockIdx.x, t = threadIdx.x;
  int chunk = (M + gridDim.x - 1) / gridDim.x;
  int m0 = b*chunk;
  int m1 = m0 + chunk; if(m1 > M) m1 = M;
  for(int c=0;c<3;c++){
    for(int n=t; n<N; n+=256) lds[n] = 0.f;
    __syncthreads();
    for(int m=m0+t; m<m1; m+=256)
      atomicAdd(&lds[neighJ[m]], -f2buf[(size_t)m*3+c]);
    __syncthreads();
    float* dst = jpart + ((size_t)b*3 + c)*N;
    for(int n=t; n<N; n+=256) dst[n] = lds[n];
    __syncthreads();
  }
}

// ---------------- K6: jab2 total -> S2 partials; Ppart -> P sum ------------------
__global__ void reduce_kernel(const float* __restrict__ Ppart, const float* __restrict__ jab2c,
                              const float* __restrict__ jpart,
                              float* __restrict__ Pacc, float* __restrict__ S2, int N){
  __shared__ float red[256];
  int tid = threadIdx.x;
  float s2[9] = {0.f,0.f,0.f,0.f,0.f,0.f,0.f,0.f,0.f};
  float pp[9] = {0.f,0.f,0.f,0.f,0.f,0.f,0.f,0.f,0.f};
  for(int n = blockIdx.x*256 + tid; n < N; n += gridDim.x*256){
    float x = jab2c[n*3+0], y = jab2c[n*3+1], z = jab2c[n*3+2];
    for(int b=0;b<NBSC;b++){
      const float* jp = jpart + (size_t)b*3*N;
      x += jp[0*(size_t)N + n];
      y += jp[1*(size_t)N + n];
      z += jp[2*(size_t)N + n];
    }
    s2[0]+=x*x; s2[1]+=x*y; s2[2]+=x*z;
    s2[3]+=y*x; s2[4]+=y*y; s2[5]+=y*z;
    s2[6]+=z*x; s2[7]+=z*y; s2[8]+=z*z;
    const float* pr = Ppart + (size_t)n*9;
    #pragma unroll
    for(int k=0;k<9;k++) pp[k] += pr[k];
  }
  #pragma unroll
  for(int k=0;k<9;k++){
    red[tid]=s2[k]; __syncthreads();
    for(int off=128; off>0; off>>=1){
      if(tid<off) red[tid]+=red[tid+off];
      __syncthreads();
    }
    if(tid==0) atomicAdd(&S2[k], red[0]);
    __syncthreads();
    red[tid]=pp[k]; __syncthreads();
    for(int off=128; off>0; off>>=1){
      if(tid<off) red[tid]+=red[tid+off];
      __syncthreads();
    }
    if(tid==0) atomicAdd(&Pacc[k], red[0]);
    __syncthreads();
  }
}

// ---------------- K7: assemble --------------------------------------------------
__global__ void final_kernel(const float* __restrict__ Pacc, const float* __restrict__ S2,
                             const float* __restrict__ e2acc, float* __restrict__ out){
  int tid = threadIdx.x;
  if(tid < 9){
    int a = tid/3, b = tid%3;
    float v = Pacc[a*3+b] + Pacc[b*3+a] + S2[tid];
    if(a==b) v += e2acc[0];
    out[tid] = v;
  }
}

extern "C" void kernel_launch(void* const* d_in, const int* in_sizes, int n_in,
                              void* d_out, int out_size, void* d_ws, size_t ws_size,
                              hipStream_t stream){
  const float* cart    = (const float*)d_in[0];
  const float* shifts  = (const float*)d_in[1];
  const float* rs      = (const float*)d_in[2];
  const float* inta    = (const float*)d_in[3];
  const float* cparams = (const float*)d_in[4];
  const float* w1 = (const float*)d_in[5];
  const float* b1 = (const float*)d_in[6];
  const float* a1 = (const float*)d_in[7];
  const float* g1 = (const float*)d_in[8];
  const float* w2 = (const float*)d_in[9];
  const float* b2 = (const float*)d_in[10];
  const float* a2 = (const float*)d_in[11];
  const float* g2 = (const float*)d_in[12];
  const float* w3 = (const float*)d_in[13];
  const float* b3 = (const float*)d_in[14];
  const float* a3 = (const float*)d_in[15];
  const float* g3 = (const float*)d_in[16];
  const float* w4 = (const float*)d_in[17];
  const float* b4 = (const float*)d_in[18];
  const float* a4 = (const float*)d_in[19];
  const float* g4 = (const float*)d_in[20];
  const float* wout = (const float*)d_in[21];
  const float* bout = (const float*)d_in[22];
  const int* species = (const int*)d_in[23];
  const int* neigh   = (const int*)d_in[24];
  float* out = (float*)d_out;

  const int N = in_sizes[0]/3;
  const int M = in_sizes[24]/2;
  const int K = M/N;
  const int* neighJ = neigh + M;

  char* base = (char*)d_ws;
  size_t off = 0;
  auto alloc = [&](size_t bytes)->void*{
    void* p = base + off;
    off = (off + bytes + 255) & ~(size_t)255;
    return p;
  };
  float*  Bws    = (float*)alloc((size_t)N*NBW*4);
  float*  G1ws   = (float*)alloc((size_t)N*D0*4);
  float*  G2ws   = (float*)alloc((size_t)N*D0*4);
  float*  Ppart  = (float*)alloc((size_t)N*9*4);
  float*  jab2c  = (float*)alloc((size_t)N*3*4);
  float*  f2buf  = (float*)alloc((size_t)M*3*4);
  float4* pairbuf= (float4*)alloc((size_t)M*16);
  float*  jpart  = (float*)alloc((size_t)NBSC*3*N*4);
  float*  acc    = (float*)alloc(32*4);          // P[0..8], S2[9..17], e2[18]
  int*    counts = (int*)alloc(2*4);
  int*    perm   = (int*)alloc((size_t)2*N*4);
  float*  WT1    = (float*)alloc((size_t)6*D0*D1*4);
  float*  WT2    = (float*)alloc((size_t)6*D1*D2*4);
  float*  WT3    = (float*)alloc((size_t)6*D2*D3*4);
  float*  WT4    = (float*)alloc((size_t)6*D3*D4*4);

  hipMemsetAsync(acc, 0, 32*4, stream);

  // allow >64KB dynamic LDS for pairs_kernel (160KB/CU on gfx950)
  size_t ldsBytes = (size_t)N*16;
  hipFuncSetAttribute((const void*)pairs_kernel,
                      hipFuncAttributeMaxDynamicSharedMemorySize, (int)ldsBytes);

  const int ETOT = 6*(D0*D1 + D1*D2 + D2*D3 + D3*D4);
  perm_kernel<<<1,256,0,stream>>>(species, perm, counts, N);
  transpose_all_kernel<<<(ETOT+255)/256,256,0,stream>>>(w1,w2,w3,w4, WT1,WT2,WT3,WT4);
  pairs_kernel<<<256,1024,ldsBytes,stream>>>(cart, shifts, species, neighJ, pairbuf, M, N, K);
  density_kernel<<<N/4,256,0,stream>>>(pairbuf, rs, inta, cparams, Bws, K);
  mlp_kernel<<<3*2*(N/AT),256,0,stream>>>(Bws, perm, counts,
      w1,b1,a1,g1, w2,b2,a2,g2, w3,b3,a3,g3, w4,b4,a4,g4, wout,bout,
      WT1,WT2,WT3,WT4, G1ws,G2ws, acc+18, N);
  pair_back_kernel<<<N/4,256,0,stream>>>(pairbuf, shifts, rs, inta, cparams,
                                         Bws, G1ws, G2ws, Ppart, jab2c, f2buf, K);
  scatter_kernel<<<NBSC,256,0,stream>>>(neighJ, f2buf, jpart, M, N);
  reduce_kernel<<<64,256,0,stream>>>(Ppart, jab2c, jpart, acc, acc+9, N);
  final_kernel<<<1,64,0,stream>>>(acc, acc+9, acc+18, out);
}

// Round 17
// 280.340 us; speedup vs baseline: 1.5067x; 1.0164x over previous
//
#include <hip/hip_runtime.h>

#define NWAVE 12
#define NL 13
#define NBW (NL*NWAVE)   // 156
#define D0 36
#define D1 256
#define D2 128
#define D3 64
#define D4 32
#define AT 16            // atoms per MLP block; 4 waves x 4 atoms, barrier-free
#define NMAX 8192
#define NBSC 128         // scatter privatization blocks
#define PI6 0.52359877559829887307f

#define F4(p) (*(const float4*)(p))
#define F2(p) (*(const float2*)(p))

// wave-local sync: drain this wave's LDS ops; no cross-wave barrier.
#define WSYNC() do{ asm volatile("s_waitcnt lgkmcnt(0)" ::: "memory"); \
                    __builtin_amdgcn_sched_barrier(0); }while(0)

__device__ __forceinline__ float wave_reduce(float v){
  #pragma unroll
  for(int o=32;o>0;o>>=1) v += __shfl_down(v,o);
  return v;
}

// ---------------- perm: stable partition of atoms by species (deterministic) ----
__global__ void perm_kernel(const int* __restrict__ species, int* __restrict__ perm,
                            int* __restrict__ counts, int N){
  __shared__ int sc[256];
  int t = threadIdx.x;
  int per = N/256;
  int c0 = 0;
  for(int k=0;k<per;k++) c0 += (species[t*per+k]==0) ? 1 : 0;
  sc[t]=c0; __syncthreads();
  for(int off=1; off<256; off<<=1){
    int add = (t>=off)? sc[t-off] : 0;
    __syncthreads();
    sc[t] += add;
    __syncthreads();
  }
  int incl = sc[t];
  int excl = incl - c0;
  int total0 = sc[255];
  if(t==0){ counts[0]=total0; counts[1]=N-total0; }
  int base0 = excl;
  int base1 = N + (t*per - excl);
  for(int k=0;k<per;k++){
    int a = t*per+k;
    if(species[a]==0) perm[base0++]=a; else perm[base1++]=a;
  }
}

// ---------------- fused weight transpose (one launch for all 4 layers) ----------
__global__ void transpose_all_kernel(const float* __restrict__ w1, const float* __restrict__ w2,
                                     const float* __restrict__ w3, const float* __restrict__ w4,
                                     float* __restrict__ t1, float* __restrict__ t2,
                                     float* __restrict__ t3, float* __restrict__ t4){
  const int E1 = 6*D0*D1, E2 = 6*D1*D2, E3 = 6*D2*D3, E4 = 6*D3*D4;
  int idx = blockIdx.x*256 + threadIdx.x;
  if(idx < E1){
    int slab = idx/(D0*D1), r = idx%(D0*D1);
    int f = r/D1, o = r%D1;
    t1[slab*D0*D1 + o*D0 + f] = w1[idx];
  } else if(idx < E1+E2){
    int k = idx-E1; int slab = k/(D1*D2), r = k%(D1*D2);
    int f = r/D2, o = r%D2;
    t2[slab*D1*D2 + o*D1 + f] = w2[k];
  } else if(idx < E1+E2+E3){
    int k = idx-E1-E2; int slab = k/(D2*D3), r = k%(D2*D3);
    int f = r/D3, o = r%D3;
    t3[slab*D2*D3 + o*D2 + f] = w3[k];
  } else if(idx < E1+E2+E3+E4){
    int k = idx-E1-E2-E3; int slab = k/(D3*D4), r = k%(D3*D4);
    int f = r/D4, o = r%D4;
    t4[slab*D3*D4 + o*D3 + f] = w4[k];
  }
}

// ---------------- K0: per-pair geometry via LDS-resident cart -------------------
__global__ void pairs_kernel(const float* __restrict__ cart, const float* __restrict__ shifts,
                             const int* __restrict__ species, const int* __restrict__ neighJ,
                             float4* __restrict__ pairbuf, int M, int N, int K){
  extern __shared__ float4 ca[];
  int t = threadIdx.x;
  for(int a=t; a<N; a+=blockDim.x)
    ca[a] = make_float4(cart[a*3+0], cart[a*3+1], cart[a*3+2], (float)species[a]);
  __syncthreads();
  int stride = gridDim.x*blockDim.x;
  for(int m = blockIdx.x*blockDim.x + t; m < M; m += stride){
    int i = m / K;
    int j = neighJ[m];
    float4 cj = ca[j];
    float4 ci = ca[i];
    float dx = ci.x - cj.x + shifts[m*3+0];
    float dy = ci.y - cj.y + shifts[m*3+1];
    float dz = ci.z - cj.z + shifts[m*3+2];
    float dist = sqrtf(dx*dx+dy*dy+dz*dz);
    float enc = (cj.w != 0.f) ? -dist : dist;
    pairbuf[m] = make_float4(dx, dy, dz, enc);
  }
}

// ---------------- K1: B[n,13,12]; 4 waves/block, one atom per wave --------------
__launch_bounds__(256, 1)
__global__ void density_kernel(const float4* __restrict__ pairbuf,
                               const float* __restrict__ rs, const float* __restrict__ inta,
                               const float* __restrict__ cparams,
                               float* __restrict__ B, int K){
  int wv = threadIdx.x >> 6;
  int t  = threadIdx.x & 63;
  int i  = blockIdx.x*4 + wv;
  __shared__ float sang[4][64][NL];
  __shared__ float sg[4][64][NWAVE];
  if(t < K){
    float4 pb = pairbuf[(size_t)i*K + t];
    float dx = pb.x, dy = pb.y, dz = pb.z;
    int sj = (pb.w < 0.f) ? 1 : 0;
    float dist = fabsf(pb.w);
    float base = 0.5f*cosf(dist*PI6)+0.5f;
    float fc = base*base;
    #pragma unroll
    for(int w=0;w<NWAVE;w++){
      float d = dist - rs[sj*NWAVE+w];
      sg[wv][t][w] = __expf(inta[sj*NWAVE+w]*d*d)*cparams[sj*NWAVE+w];
    }
    sang[wv][t][0]=fc;
    sang[wv][t][1]=fc*dx;  sang[wv][t][2]=fc*dy;  sang[wv][t][3]=fc*dz;
    sang[wv][t][4]=fc*dx*dx; sang[wv][t][5]=fc*dx*dy; sang[wv][t][6]=fc*dx*dz;
    sang[wv][t][7]=fc*dy*dx; sang[wv][t][8]=fc*dy*dy; sang[wv][t][9]=fc*dy*dz;
    sang[wv][t][10]=fc*dz*dx; sang[wv][t][11]=fc*dz*dy; sang[wv][t][12]=fc*dz*dz;
  }
  __syncthreads();
  for(int idx=t; idx<NBW; idx+=64){
    int l = idx/NWAVE, w = idx%NWAVE;
    float s = 0.f;
    for(int k=0;k<K;k++) s += sang[wv][k][l]*sg[wv][k][w];
    B[(size_t)i*NBW+idx] = s;
  }
}

// ---------------- K3: BARRIER-FREE MLP: 4 waves x 4 atoms, wave-private LDS -----
// All dz reuse buffers use the FORWARD row stride (D3/D1/D2/D1) so every row
// stays wave-private — fixes the R16 cross-wave aliasing race (dz4 stride 32
// overlapped other waves' forward H3 stride-64 rows).
__launch_bounds__(256, 1)
__global__ void mlp_kernel(const float* __restrict__ B,
    const int* __restrict__ perm, const int* __restrict__ counts,
    const float* __restrict__ w1,const float* __restrict__ b1,const float* __restrict__ a1,const float* __restrict__ g1,
    const float* __restrict__ w2,const float* __restrict__ b2,const float* __restrict__ a2,const float* __restrict__ g2,
    const float* __restrict__ w3,const float* __restrict__ b3,const float* __restrict__ a3,const float* __restrict__ g3,
    const float* __restrict__ w4,const float* __restrict__ b4,const float* __restrict__ a4,const float* __restrict__ g4,
    const float* __restrict__ wout,const float* __restrict__ bout,
    const float* __restrict__ wt1,const float* __restrict__ wt2,const float* __restrict__ wt3,const float* __restrict__ wt4,
    float* __restrict__ G1, float* __restrict__ G2, float* __restrict__ e2acc, int N)
{
  const int bpt = N/AT;
  const int net = blockIdx.x / (2*bpt);
  const int rem = blockIdx.x % (2*bpt);
  const int typ = rem / bpt;
  const int sbase = (rem % bpt)*AT;
  const int cnt = counts[typ];
  if(sbase >= cnt) return;
  const int tid = threadIdx.x;
  const int wv  = tid >> 6;
  const int ln  = tid & 63;
  const int r0  = wv*4;             // this wave's atom rows
  const int slab = net*2 + typ;

  __shared__ __align__(16) float X[AT][D0];
  __shared__ __align__(16) float H1s[AT*D1];
  __shared__ __align__(16) float H2s[AT*D2];
  __shared__ __align__(16) float H3s[AT*D3];
  __shared__ __align__(16) float H4s[AT*D4];
  __shared__ int atomsS[AT];

  if(ln < 4){
    int slot = sbase + r0 + ln;
    atomsS[r0+ln] = (slot < cnt) ? perm[typ*N + slot] : -1;
  }
  WSYNC();

  // density features (wave builds its own 4 rows)
  for(int idx=ln; idx<4*D0; idx+=64){
    int r = idx/D0, f = idx%D0;
    int a = atomsS[r0+r];
    float v = 0.f;
    if(a >= 0){
      int w = f%NWAVE, grp = f/NWAVE;
      const float* Br = B + a*NBW;
      if(grp==0){ float b0=Br[w]; v=b0*b0; }
      else if(grp==1){
        #pragma unroll
        for(int l=1;l<4;l++){ float b0=Br[l*NWAVE+w]; v += b0*b0; }
      } else {
        #pragma unroll
        for(int l=4;l<13;l++){ float b0=Br[l*NWAVE+w]; v += b0*b0; }
      }
    }
    X[r0+r][f] = v;
  }
  WSYNC();

  // lane-ownership maps (within wave; same fwd & bwd)
  const int l1c = ln*4;             // L1/dz1: 4 rows x 4 cols
  const int l2c = ln*2;             // L2/dz2: 4 rows x 2 cols
  const int l3c = ln;               // L3/dz3: 4 rows x 1 col
  const int l4c = ln & 31;          // L4/dz4: 2 rows x 1 col
  const int l4r = (ln >> 5)*2;

  float A1r[4][4], A2r[4][2], A3r[4], A4r[2];

  // ---- L1: 36 -> 256, 4 rows x 4 cols
  {
    const float* W = w1 + slab*D0*D1;
    float acc[4][4];
    {
      float4 bv = F4(&b1[slab*D1+l1c]);
      #pragma unroll
      for(int rr=0;rr<4;rr++){ acc[rr][0]=bv.x; acc[rr][1]=bv.y; acc[rr][2]=bv.z; acc[rr][3]=bv.w; }
    }
    #pragma unroll
    for(int kk=0; kk<D0/4; kk++){
      float4 wa = F4(&W[(kk*4+0)*D1+l1c]);
      float4 wb = F4(&W[(kk*4+1)*D1+l1c]);
      float4 wc = F4(&W[(kk*4+2)*D1+l1c]);
      float4 wd = F4(&W[(kk*4+3)*D1+l1c]);
      #pragma unroll
      for(int rr=0;rr<4;rr++){
        float4 xv = F4(&X[r0+rr][kk*4]);
        acc[rr][0] += xv.x*wa.x + xv.y*wb.x + xv.z*wc.x + xv.w*wd.x;
        acc[rr][1] += xv.x*wa.y + xv.y*wb.y + xv.z*wc.y + xv.w*wd.y;
        acc[rr][2] += xv.x*wa.z + xv.y*wb.z + xv.z*wc.z + xv.w*wd.z;
        acc[rr][3] += xv.x*wa.w + xv.y*wb.w + xv.z*wc.w + xv.w*wd.w;
      }
    }
    float4 av4 = F4(&a1[slab*D1+l1c]);
    float4 gv4 = F4(&g1[slab*D1+l1c]);
    float avv[4] = {av4.x, av4.y, av4.z, av4.w};
    float gvv[4] = {gv4.x, gv4.y, gv4.z, gv4.w};
    #pragma unroll
    for(int rr=0;rr<4;rr++){
      float hp[4];
      #pragma unroll
      for(int cc=0;cc<4;cc++){
        float u = gvv[cc]*acc[rr][cc];
        float s = 1.f/(1.f+__expf(-u));
        hp[cc] = avv[cc]*u*s;
        A1r[rr][cc] = avv[cc]*gvv[cc]*s*(1.f + u*(1.f-s));
      }
      float4 h; h.x=hp[0]; h.y=hp[1]; h.z=hp[2]; h.w=hp[3];
      *(float4*)&H1s[(r0+rr)*D1 + l1c] = h;
    }
  }
  WSYNC();
  // ---- L2: 256 -> 128, 4 rows x 2 cols
  {
    const float* W = w2 + slab*D1*D2;
    float acc[4][2];
    {
      float2 bv = F2(&b2[slab*D2+l2c]);
      #pragma unroll
      for(int rr=0;rr<4;rr++){ acc[rr][0]=bv.x; acc[rr][1]=bv.y; }
    }
    for(int kk=0; kk<D1/4; kk++){
      float2 wa = F2(&W[(kk*4+0)*D2+l2c]);
      float2 wb = F2(&W[(kk*4+1)*D2+l2c]);
      float2 wc = F2(&W[(kk*4+2)*D2+l2c]);
      float2 wd = F2(&W[(kk*4+3)*D2+l2c]);
      #pragma unroll
      for(int rr=0;rr<4;rr++){
        float4 hv = F4(&H1s[(r0+rr)*D1 + kk*4]);
        acc[rr][0] += hv.x*wa.x + hv.y*wb.x + hv.z*wc.x + hv.w*wd.x;
        acc[rr][1] += hv.x*wa.y + hv.y*wb.y + hv.z*wc.y + hv.w*wd.y;
      }
    }
    float2 av2 = F2(&a2[slab*D2+l2c]);
    float2 gv2 = F2(&g2[slab*D2+l2c]);
    float avv[2] = {av2.x, av2.y};
    float gvv[2] = {gv2.x, gv2.y};
    #pragma unroll
    for(int rr=0;rr<4;rr++){
      float hp[2];
      #pragma unroll
      for(int cc=0;cc<2;cc++){
        float u = gvv[cc]*acc[rr][cc];
        float s = 1.f/(1.f+__expf(-u));
        hp[cc] = avv[cc]*u*s;
        A2r[rr][cc] = avv[cc]*gvv[cc]*s*(1.f + u*(1.f-s));
      }
      float2 h; h.x=hp[0]; h.y=hp[1];
      *(float2*)&H2s[(r0+rr)*D2 + l2c] = h;
    }
  }
  WSYNC();
  // ---- L3: 128 -> 64, 4 rows x 1 col
  {
    const float* W = w3 + slab*D2*D3;
    float bias = b3[slab*D3+l3c];
    float acc[4] = {bias, bias, bias, bias};
    for(int kk=0; kk<D2/4; kk++){
      float wa = W[(kk*4+0)*D3+l3c];
      float wb = W[(kk*4+1)*D3+l3c];
      float wc = W[(kk*4+2)*D3+l3c];
      float wd = W[(kk*4+3)*D3+l3c];
      #pragma unroll
      for(int rr=0;rr<4;rr++){
        float4 hv = F4(&H2s[(r0+rr)*D2 + kk*4]);
        acc[rr] += hv.x*wa + hv.y*wb + hv.z*wc + hv.w*wd;
      }
    }
    float av = a3[slab*D3+l3c], gv = g3[slab*D3+l3c];
    #pragma unroll
    for(int rr=0;rr<4;rr++){
      float u = gv*acc[rr];
      float s = 1.f/(1.f+__expf(-u));
      H3s[(r0+rr)*D3+l3c] = av*u*s;
      A3r[rr] = av*gv*s*(1.f + u*(1.f-s));
    }
  }
  WSYNC();
  // ---- L4: 64 -> 32, 2 rows x 1 col
  {
    const float* W = w4 + slab*D3*D4;
    float bias = b4[slab*D4+l4c];
    float acc[2] = {bias, bias};
    for(int kk=0; kk<D3/4; kk++){
      float wa = W[(kk*4+0)*D4+l4c];
      float wb = W[(kk*4+1)*D4+l4c];
      float wc = W[(kk*4+2)*D4+l4c];
      float wd = W[(kk*4+3)*D4+l4c];
      #pragma unroll
      for(int rr=0;rr<2;rr++){
        float4 hv = F4(&H3s[(r0+l4r+rr)*D3 + kk*4]);
        acc[rr] += hv.x*wa + hv.y*wb + hv.z*wc + hv.w*wd;
      }
    }
    float av = a4[slab*D4+l4c], gv = g4[slab*D4+l4c];
    #pragma unroll
    for(int rr=0;rr<2;rr++){
      float u = gv*acc[rr];
      float s = 1.f/(1.f+__expf(-u));
      H4s[(r0+l4r+rr)*D4+l4c] = av*u*s;
      A4r[rr] = av*gv*s*(1.f + u*(1.f-s));
    }
  }
  WSYNC();
  // ---- output layer (+ e2 for net 2)
  if(net == 2){
    const float* wo = wout + slab*D4;
    float val = 0.f;
    if(ln < 4){
      int a = atomsS[r0+ln];
      if(a >= 0){
        float s = bout[slab];
        const float* hr = &H4s[(r0+ln)*D4];
        #pragma unroll
        for(int f=0;f<D4;f++) s += hr[f]*wo[f];
        val = s;
      }
    }
    float v = wave_reduce(val);
    if(ln==0) atomicAdd(e2acc, v);
  }
  // ---- backward for nets 0,1: G = dE/ddensity
  if(net < 2){
    float* __restrict__ Gout = (net==0)? G1 : G2;
    const float* wo = wout + slab*D4;
    // dz4 -> H3s rows at FORWARD stride D3 (cols 0..31): wave-private reuse
    {
      float wv4 = wo[l4c];
      H3s[(r0+l4r+0)*D3+l4c] = wv4 * A4r[0];
      H3s[(r0+l4r+1)*D3+l4c] = wv4 * A4r[1];
    }
    WSYNC();
    // dz3 = (dz4 @ W4^T)*A3 -> H1s rows at stride D1 (cols 0..63)
    {
      const float* WT = wt4 + slab*D4*D3;   // [32][64]
      float acc[4] = {0.f,0.f,0.f,0.f};
      #pragma unroll
      for(int kk=0; kk<D4/4; kk++){
        float wa = WT[(kk*4+0)*D3+l3c];
        float wb = WT[(kk*4+1)*D3+l3c];
        float wc = WT[(kk*4+2)*D3+l3c];
        float wd = WT[(kk*4+3)*D3+l3c];
        #pragma unroll
        for(int rr=0;rr<4;rr++){
          float4 dv = F4(&H3s[(r0+rr)*D3 + kk*4]);
          acc[rr] += dv.x*wa + dv.y*wb + dv.z*wc + dv.w*wd;
        }
      }
      #pragma unroll
      for(int rr=0;rr<4;rr++)
        H1s[(r0+rr)*D1+l3c] = acc[rr]*A3r[rr];
    }
    WSYNC();
    // dz2 = (dz3 @ W3^T)*A2 -> H2s rows at stride D2 (cols 0..127)
    {
      const float* WT = wt3 + slab*D3*D2;   // [64][128]
      float acc[4][2] = {{0.f,0.f},{0.f,0.f},{0.f,0.f},{0.f,0.f}};
      for(int kk=0; kk<D3/4; kk++){
        float2 wa = F2(&WT[(kk*4+0)*D2+l2c]);
        float2 wb = F2(&WT[(kk*4+1)*D2+l2c]);
        float2 wc = F2(&WT[(kk*4+2)*D2+l2c]);
        float2 wd = F2(&WT[(kk*4+3)*D2+l2c]);
        #pragma unroll
        for(int rr=0;rr<4;rr++){
          float4 dv = F4(&H1s[(r0+rr)*D1 + kk*4]);
          acc[rr][0] += dv.x*wa.x + dv.y*wb.x + dv.z*wc.x + dv.w*wd.x;
          acc[rr][1] += dv.x*wa.y + dv.y*wb.y + dv.z*wc.y + dv.w*wd.y;
        }
      }
      #pragma unroll
      for(int rr=0;rr<4;rr++){
        float2 h;
        h.x = acc[rr][0]*A2r[rr][0];
        h.y = acc[rr][1]*A2r[rr][1];
        *(float2*)&H2s[(r0+rr)*D2 + l2c] = h;
      }
    }
    WSYNC();
    // dz1 = (dz2 @ W2^T)*A1 -> H1s rows at stride D1 (cols 0..255)
    {
      const float* WT = wt2 + slab*D2*D1;   // [128][256]
      float acc[4][4];
      #pragma unroll
      for(int rr=0;rr<4;rr++){ acc[rr][0]=0.f; acc[rr][1]=0.f; acc[rr][2]=0.f; acc[rr][3]=0.f; }
      for(int kk=0; kk<D2/4; kk++){
        float4 wa = F4(&WT[(kk*4+0)*D1+l1c]);
        float4 wb = F4(&WT[(kk*4+1)*D1+l1c]);
        float4 wc = F4(&WT[(kk*4+2)*D1+l1c]);
        float4 wd = F4(&WT[(kk*4+3)*D1+l1c]);
        #pragma unroll
        for(int rr=0;rr<4;rr++){
          float4 dv = F4(&H2s[(r0+rr)*D2 + kk*4]);
          acc[rr][0] += dv.x*wa.x + dv.y*wb.x + dv.z*wc.x + dv.w*wd.x;
          acc[rr][1] += dv.x*wa.y + dv.y*wb.y + dv.z*wc.y + dv.w*wd.y;
          acc[rr][2] += dv.x*wa.z + dv.y*wb.z + dv.z*wc.z + dv.w*wd.z;
          acc[rr][3] += dv.x*wa.w + dv.y*wb.w + dv.z*wc.w + dv.w*wd.w;
        }
      }
      #pragma unroll
      for(int rr=0;rr<4;rr++){
        float4 h;
        h.x = acc[rr][0]*A1r[rr][0];
        h.y = acc[rr][1]*A1r[rr][1];
        h.z = acc[rr][2]*A1r[rr][2];
        h.w = acc[rr][3]*A1r[rr][3];
        *(float4*)&H1s[(r0+rr)*D1 + l1c] = h;
      }
    }
    WSYNC();
    // G = dz1 @ W1^T  (wave writes its own 4 rows)
    {
      const float* WT = wt1 + slab*D1*D0;
      for(int idx=ln; idx<4*D0; idx+=64){
        int r = idx/D0, f = idx%D0;
        const float* dr = &H1s[(r0+r)*D1];
        float acc = 0.f;
        for(int oo=0; oo<D1; oo+=4){
          const float4 dv = F4(&dr[oo]);
          acc += dv.x*WT[(oo+0)*D0+f] + dv.y*WT[(oo+1)*D0+f]
               + dv.z*WT[(oo+2)*D0+f] + dv.w*WT[(oo+3)*D0+f];
        }
        int a = atomsS[r0+r];
        if(a >= 0) Gout[a*D0+f] = acc;
      }
    }
  }
}

// ---------------- K4: per-pair backward; 4 waves/block, one atom per wave -------
__launch_bounds__(256, 1)
__global__ void pair_back_kernel(const float4* __restrict__ pairbuf,
                                 const float* __restrict__ shifts,
                                 const float* __restrict__ rs, const float* __restrict__ inta,
                                 const float* __restrict__ cparams,
                                 const float* __restrict__ B,
                                 const float* __restrict__ G1, const float* __restrict__ G2,
                                 float* __restrict__ Ppart, float* __restrict__ jab2c,
                                 float* __restrict__ f2buf, int K){
  int wv = threadIdx.x >> 6;
  int t  = threadIdx.x & 63;
  int i  = blockIdx.x*4 + wv;
  __shared__ float E1[4][NBW], E2[4][NBW];
  for(int idx=t; idx<NBW; idx+=64){
    int l = idx/NWAVE, w = idx%NWAVE;
    int grp = (l==0) ? 0 : ((l<4) ? 1 : 2);
    float b = B[(size_t)i*NBW+idx];
    E1[wv][idx] = 2.f*b*G1[(size_t)i*D0 + grp*NWAVE + w];
    E2[wv][idx] = 2.f*b*G2[(size_t)i*D0 + grp*NWAVE + w];
  }
  __syncthreads();
  float p[9] = {0.f,0.f,0.f,0.f,0.f,0.f,0.f,0.f,0.f};
  float fi2[3] = {0.f,0.f,0.f};
  if(t < K){
    int m = i*K + t;
    float4 pb = pairbuf[(size_t)m];
    float dx = pb.x, dy = pb.y, dz = pb.z;
    int sj = (pb.w < 0.f) ? 1 : 0;
    float dist = fabsf(pb.w);
    float shx = shifts[m*3+0], shy = shifts[m*3+1], shz = shifts[m*3+2];
    float invd = 1.f/dist;
    float u = dist*PI6;
    float base = 0.5f*cosf(u)+0.5f;
    float fc = base*base;
    float fcp = -PI6*sinf(u)*base;      // d fc / d dist
    float gs[NWAVE], tw[NWAVE];
    #pragma unroll
    for(int w=0;w<NWAVE;w++){
      float d = dist - rs[sj*NWAVE+w];
      float ia = inta[sj*NWAVE+w];
      float g = __expf(ia*d*d)*cparams[sj*NWAVE+w];
      gs[w] = g;
      tw[w] = fcp*g + fc*(2.f*ia*d*g);  // d(fc*gauss)/d dist factor
    }
    float mono[NL] = {1.f, dx,dy,dz, dx*dx,dx*dy,dx*dz, dy*dx,dy*dy,dy*dz, dz*dx,dz*dy,dz*dz};
    float f1[3], f2[3];
    for(int net=0; net<2; net++){
      const float* E = net ? E2[wv] : E1[wv];
      float sl[NL];
      float radial = 0.f;
      #pragma unroll
      for(int l=0;l<NL;l++){
        float s = 0.f, q = 0.f;
        #pragma unroll
        for(int w=0;w<NWAVE;w++){
          float e = E[l*NWAVE+w];
          s += e*gs[w];
          q += e*tw[w];
        }
        sl[l] = s;
        radial += mono[l]*q;
      }
      float Ax = sl[1] + 2.f*sl[4]*dx + (sl[5]+sl[7])*dy + (sl[6]+sl[10])*dz;
      float Ay = sl[2] + (sl[5]+sl[7])*dx + 2.f*sl[8]*dy + (sl[9]+sl[11])*dz;
      float Az = sl[3] + (sl[6]+sl[10])*dx + (sl[9]+sl[11])*dy + 2.f*sl[12]*dz;
      float rr = radial*invd;
      float fx = dx*rr + fc*Ax;
      float fy = dy*rr + fc*Ay;
      float fz = dz*rr + fc*Az;
      if(net==0){ f1[0]=fx; f1[1]=fy; f1[2]=fz; }
      else      { f2[0]=fx; f2[1]=fy; f2[2]=fz; }
    }
    // cart[i]-cart[j] = dvec - shift ;  P += (cart_i - cart_j) (x) f1
    float cx = dx-shx, cy = dy-shy, cz = dz-shz;
    p[0]=cx*f1[0]; p[1]=cx*f1[1]; p[2]=cx*f1[2];
    p[3]=cy*f1[0]; p[4]=cy*f1[1]; p[5]=cy*f1[2];
    p[6]=cz*f1[0]; p[7]=cz*f1[1]; p[8]=cz*f1[2];
    // per-pair neighbor force (gathered by scatter_kernel in LDS)
    float* fb = f2buf + (size_t)m*3;
    fb[0]=f2[0]; fb[1]=f2[1]; fb[2]=f2[2];
    fi2[0]=f2[0]; fi2[1]=f2[1]; fi2[2]=f2[2];
  }
  #pragma unroll
  for(int k=0;k<9;k++){
    float v = wave_reduce(p[k]);
    if(t==0) Ppart[(size_t)i*9+k] = v;
  }
  #pragma unroll
  for(int c=0;c<3;c++){
    float v = wave_reduce(fi2[c]);
    if(t==0) jab2c[(size_t)i*3+c] = v;
  }
}

// ---------------- K5: LDS-privatized scatter of -f2 onto neighbor atoms ---------
__global__ void scatter_kernel(const int* __restrict__ neighJ, const float* __restrict__ f2buf,
                               float* __restrict__ jpart, int M, int N){
  __shared__ float lds[NMAX];
  int b = blockIdx.x, t = threadIdx.x;
  int chunk = (M + gridDim.x - 1) / gridDim.x;
  int m0 = b*chunk;
  int m1 = m0 + chunk; if(m1 > M) m1 = M;
  for(int c=0;c<3;c++){
    for(int n=t; n<N; n+=256) lds[n] = 0.f;
    __syncthreads();
    for(int m=m0+t; m<m1; m+=256)
      atomicAdd(&lds[neighJ[m]], -f2buf[(size_t)m*3+c]);
    __syncthreads();
    float* dst = jpart + ((size_t)b*3 + c)*N;
    for(int n=t; n<N; n+=256) dst[n] = lds[n];
    __syncthreads();
  }
}

// ---------------- K6: jab2 total -> S2 partials; Ppart -> P sum ------------------
__global__ void reduce_kernel(const float* __restrict__ Ppart, const float* __restrict__ jab2c,
                              const float* __restrict__ jpart,
                              float* __restrict__ Pacc, float* __restrict__ S2, int N){
  __shared__ float red[256];
  int tid = threadIdx.x;
  float s2[9] = {0.f,0.f,0.f,0.f,0.f,0.f,0.f,0.f,0.f};
  float pp[9] = {0.f,0.f,0.f,0.f,0.f,0.f,0.f,0.f,0.f};
  for(int n = blockIdx.x*256 + tid; n < N; n += gridDim.x*256){
    float x = jab2c[n*3+0], y = jab2c[n*3+1], z = jab2c[n*3+2];
    for(int b=0;b<NBSC;b++){
      const float* jp = jpart + (size_t)b*3*N;
      x += jp[0*(size_t)N + n];
      y += jp[1*(size_t)N + n];
      z += jp[2*(size_t)N + n];
    }
    s2[0]+=x*x; s2[1]+=x*y; s2[2]+=x*z;
    s2[3]+=y*x; s2[4]+=y*y; s2[5]+=y*z;
    s2[6]+=z*x; s2[7]+=z*y; s2[8]+=z*z;
    const float* pr = Ppart + (size_t)n*9;
    #pragma unroll
    for(int k=0;k<9;k++) pp[k] += pr[k];
  }
  #pragma unroll
  for(int k=0;k<9;k++){
    red[tid]=s2[k]; __syncthreads();
    for(int off=128; off>0; off>>=1){
      if(tid<off) red[tid]+=red[tid+off];
      __syncthreads();
    }
    if(tid==0) atomicAdd(&S2[k], red[0]);
    __syncthreads();
    red[tid]=pp[k]; __syncthreads();
    for(int off=128; off>0; off>>=1){
      if(tid<off) red[tid]+=red[tid+off];
      __syncthreads();
    }
    if(tid==0) atomicAdd(&Pacc[k], red[0]);
    __syncthreads();
  }
}

// ---------------- K7: assemble --------------------------------------------------
__global__ void final_kernel(const float* __restrict__ Pacc, const float* __restrict__ S2,
                             const float* __restrict__ e2acc, float* __restrict__ out){
  int tid = threadIdx.x;
  if(tid < 9){
    int a = tid/3, b = tid%3;
    float v = Pacc[a*3+b] + Pacc[b*3+a] + S2[tid];
    if(a==b) v += e2acc[0];
    out[tid] = v;
  }
}

extern "C" void kernel_launch(void* const* d_in, const int* in_sizes, int n_in,
                              void* d_out, int out_size, void* d_ws, size_t ws_size,
                              hipStream_t stream){
  const float* cart    = (const float*)d_in[0];
  const float* shifts  = (const float*)d_in[1];
  const float* rs      = (const float*)d_in[2];
  const float* inta    = (const float*)d_in[3];
  const float* cparams = (const float*)d_in[4];
  const float* w1 = (const float*)d_in[5];
  const float* b1 = (const float*)d_in[6];
  const float* a1 = (const float*)d_in[7];
  const float* g1 = (const float*)d_in[8];
  const float* w2 = (const float*)d_in[9];
  const float* b2 = (const float*)d_in[10];
  const float* a2 = (const float*)d_in[11];
  const float* g2 = (const float*)d_in[12];
  const float* w3 = (const float*)d_in[13];
  const float* b3 = (const float*)d_in[14];
  const float* a3 = (const float*)d_in[15];
  const float* g3 = (const float*)d_in[16];
  const float* w4 = (const float*)d_in[17];
  const float* b4 = (const float*)d_in[18];
  const float* a4 = (const float*)d_in[19];
  const float* g4 = (const float*)d_in[20];
  const float* wout = (const float*)d_in[21];
  const float* bout = (const float*)d_in[22];
  const int* species = (const int*)d_in[23];
  const int* neigh   = (const int*)d_in[24];
  float* out = (float*)d_out;

  const int N = in_sizes[0]/3;
  const int M = in_sizes[24]/2;
  const int K = M/N;
  const int* neighJ = neigh + M;

  char* base = (char*)d_ws;
  size_t off = 0;
  auto alloc = [&](size_t bytes)->void*{
    void* p = base + off;
    off = (off + bytes + 255) & ~(size_t)255;
    return p;
  };
  float*  Bws    = (float*)alloc((size_t)N*NBW*4);
  float*  G1ws   = (float*)alloc((size_t)N*D0*4);
  float*  G2ws   = (float*)alloc((size_t)N*D0*4);
  float*  Ppart  = (float*)alloc((size_t)N*9*4);
  float*  jab2c  = (float*)alloc((size_t)N*3*4);
  float*  f2buf  = (float*)alloc((size_t)M*3*4);
  float4* pairbuf= (float4*)alloc((size_t)M*16);
  float*  jpart  = (float*)alloc((size_t)NBSC*3*N*4);
  float*  acc    = (float*)alloc(32*4);          // P[0..8], S2[9..17], e2[18]
  int*    counts = (int*)alloc(2*4);
  int*    perm   = (int*)alloc((size_t)2*N*4);
  float*  WT1    = (float*)alloc((size_t)6*D0*D1*4);
  float*  WT2    = (float*)alloc((size_t)6*D1*D2*4);
  float*  WT3    = (float*)alloc((size_t)6*D2*D3*4);
  float*  WT4    = (float*)alloc((size_t)6*D3*D4*4);

  hipMemsetAsync(acc, 0, 32*4, stream);

  // allow >64KB dynamic LDS for pairs_kernel (160KB/CU on gfx950)
  size_t ldsBytes = (size_t)N*16;
  hipFuncSetAttribute((const void*)pairs_kernel,
                      hipFuncAttributeMaxDynamicSharedMemorySize, (int)ldsBytes);

  const int ETOT = 6*(D0*D1 + D1*D2 + D2*D3 + D3*D4);
  perm_kernel<<<1,256,0,stream>>>(species, perm, counts, N);
  transpose_all_kernel<<<(ETOT+255)/256,256,0,stream>>>(w1,w2,w3,w4, WT1,WT2,WT3,WT4);
  pairs_kernel<<<256,1024,ldsBytes,stream>>>(cart, shifts, species, neighJ, pairbuf, M, N, K);
  density_kernel<<<N/4,256,0,stream>>>(pairbuf, rs, inta, cparams, Bws, K);
  mlp_kernel<<<3*2*(N/AT),256,0,stream>>>(Bws, perm, counts,
      w1,b1,a1,g1, w2,b2,a2,g2, w3,b3,a3,g3, w4,b4,a4,g4, wout,bout,
      WT1,WT2,WT3,WT4, G1ws,G2ws, acc+18, N);
  pair_back_kernel<<<N/4,256,0,stream>>>(pairbuf, shifts, rs, inta, cparams,
                                         Bws, G1ws, G2ws, Ppart, jab2c, f2buf, K);
  scatter_kernel<<<NBSC,256,0,stream>>>(neighJ, f2buf, jpart, M, N);
  reduce_kernel<<<64,256,0,stream>>>(Ppart, jab2c, jpart, acc, acc+9, N);
  final_kernel<<<1,64,0,stream>>>(acc, acc+9, acc+18, out);
}